// Round 8
// baseline (435.860 us; speedup 1.0000x reference)
//
#include <hip/hip_runtime.h>
#include <math.h>

#define N_NODES 50000
#define N_EDGES 800000
#define HDIM 128
#define KD 256   // K*D

typedef float f32x4 __attribute__((ext_vector_type(4)));
typedef short s16x8 __attribute__((ext_vector_type(8)));

__device__ __forceinline__ ushort f2b(float f) {        // fp32 -> bf16 RNE
    union { float f; unsigned u; } x; x.f = f;
    unsigned u = x.u;
    return (ushort)((u + 0x7FFF + ((u >> 16) & 1)) >> 16);
}
__device__ __forceinline__ float b2f(ushort h) {
    union { unsigned u; float f; } x; x.u = ((unsigned)h) << 16; return x.f;
}
__device__ __forceinline__ ushort f2h(float f) {        // fp32 -> fp16 RNE
    union { _Float16 h; ushort u; } x; x.h = (_Float16)f; return x.u;
}
__device__ __forceinline__ float h2f(ushort u) {
    union { ushort u; _Float16 h; } x; x.u = u; return (float)x.h;
}

// ------------------------------------------------------------------ CSR build
__global__ void zero_int(int* __restrict__ p, int n) {
    int i = blockIdx.x * blockDim.x + threadIdx.x;
    if (i < n) p[i] = 0;
}

__global__ void count_deg(const int* __restrict__ dst, int* __restrict__ cnt, int e) {
    int i = blockIdx.x * blockDim.x + threadIdx.x;
    if (i < e) atomicAdd(&cnt[dst[i]], 1);
}

__global__ void calc_dinv(const int* __restrict__ cnt, float* __restrict__ dinv, int n) {
    int i = blockIdx.x * blockDim.x + threadIdx.x;
    if (i < n) dinv[i] = rsqrtf((float)(cnt[i] + 1));
}

__global__ __launch_bounds__(1024)
void scan_blk(const int* __restrict__ cnt, int* __restrict__ offsets,
              int* __restrict__ blocksum, int n) {
    __shared__ int wsum[16];
    int tid = threadIdx.x;
    int i = blockIdx.x * 1024 + tid;
    int lane = tid & 63, wid = tid >> 6;
    int v = (i < n) ? cnt[i] : 0;
    int x = v;
    #pragma unroll
    for (int off = 1; off < 64; off <<= 1) {
        int t = __shfl_up(x, off, 64);
        if (lane >= off) x += t;
    }
    if (lane == 63) wsum[wid] = x;
    __syncthreads();
    if (wid == 0) {
        int w = (lane < 16) ? wsum[lane] : 0;
        #pragma unroll
        for (int off = 1; off < 16; off <<= 1) {
            int t = __shfl_up(w, off, 64);
            if (lane >= off) w += t;
        }
        if (lane < 16) wsum[lane] = w;
    }
    __syncthreads();
    int waveoff = (wid > 0) ? wsum[wid - 1] : 0;
    if (i < n) offsets[i] = x + waveoff - v;
    if (tid == 1023) blocksum[blockIdx.x] = x + waveoff;
}

__global__ void scan_top(const int* __restrict__ blocksum, int* __restrict__ blockpref,
                         int* __restrict__ offsets, int nb, int n) {
    int lane = threadIdx.x;
    int v = (lane < nb) ? blocksum[lane] : 0;
    int x = v;
    #pragma unroll
    for (int off = 1; off < 64; off <<= 1) {
        int t = __shfl_up(x, off, 64);
        if (lane >= off) x += t;
    }
    if (lane < nb) blockpref[lane] = x - v;
    if (lane == 63) offsets[n] = x;
}

__global__ __launch_bounds__(1024)
void scan_add(int* __restrict__ offsets, int* __restrict__ cursor,
              const int* __restrict__ blockpref, int n) {
    int i = blockIdx.x * 1024 + threadIdx.x;
    if (i < n) {
        int o = offsets[i] + blockpref[blockIdx.x];
        offsets[i] = o;
        cursor[i] = o;
    }
}

__global__ void fill_csr(const int* __restrict__ src, const int* __restrict__ dst,
                         int* __restrict__ cursor, int* __restrict__ csr, int e) {
    int i = blockIdx.x * blockDim.x + threadIdx.x;
    if (i < e) {
        int d = dst[i];
        int pos = atomicAdd(&cursor[d], 1);
        csr[pos] = src[i];
    }
}

// deterministic edge order per node (atomics scramble it run-to-run)
__global__ void sort_csr(int* __restrict__ csr, const int* __restrict__ offsets, int n) {
    int node = blockIdx.x * 256 + threadIdx.x;
    if (node >= n) return;
    int beg = offsets[node], end = offsets[node + 1];
    for (int i = beg + 1; i < end; ++i) {
        int key = csr[i];
        int j = i - 1;
        while (j >= beg && csr[j] > key) { csr[j + 1] = csr[j]; --j; }
        csr[j + 1] = key;
    }
}

// ------------------------------------------------------------------ prep
// x (fp32) -> fp16 gather table, pre-scaled by dinv[row]
__global__ void conv_x(const float4* __restrict__ x, ushort4* __restrict__ o,
                       const float* __restrict__ dinv, int n4) {
    int i = blockIdx.x * 256 + threadIdx.x;
    if (i >= n4) return;
    int row = i >> 5;
    float dv = dinv[row];
    float4 v = x[i];
    ushort4 u;
    u.x = f2h(v.x * dv); u.y = f2h(v.y * dv);
    u.z = f2h(v.z * dv); u.w = f2h(v.w * dv);
    o[i] = u;
}

// weights -> bf16 transposed: W1T[n][k], W2T[n][k], Bt3[k][n(mu|lv)][h]
__global__ void prep_w(const float* __restrict__ W1, const float* __restrict__ W2,
                       const float* __restrict__ Wmu, const float* __restrict__ Wlv,
                       ushort* __restrict__ w1t, ushort* __restrict__ w2t,
                       ushort* __restrict__ bt3) {
    int i = blockIdx.x * 256 + threadIdx.x;
    if (i < 16384) {
        int nn = i >> 7, k = i & 127;
        w1t[i] = f2b(W1[k * 128 + nn]);
    } else if (i < 32768) {
        int j = i - 16384; int nn = j >> 7, k = j & 127;
        w2t[j] = f2b(W2[k * 128 + nn]);
    } else if (i < 98304) {
        int j = i - 32768;                 // ((k*128 + n)*128 + h)
        int h = j & 127; int nk = j >> 7; int nn = nk & 127; int k = nk >> 7;
        float v = (nn < 64) ? Wmu[k * 8192 + h * 64 + nn]
                            : Wlv[k * 8192 + h * 64 + (nn - 64)];
        bt3[j] = f2b(v);
    }
}

// ------------------------------------------------------------------ propagate
// reads fp16 table (rows pre-scaled by dinv[src]), writes FP32:
// out[i] = dinv[i] * (sum_nbr tab[s] + tab[i])
// wave = 1 node; 4x16-lane groups; 2-deep chains (round-3-proven structure)
__global__ __launch_bounds__(256)
void prop_b(const ushort* __restrict__ hin, float* __restrict__ hout,
            const int* __restrict__ csr, const int* __restrict__ offsets,
            const float* __restrict__ dinv, int n) {
    int gw = blockIdx.x * 4 + (threadIdx.x >> 6);
    if (gw >= n) return;
    int lane = threadIdx.x & 63;
    int grp = lane >> 4, gl = lane & 15;
    int coff = gl << 3;               // element offset within row
    int beg = offsets[gw], end = offsets[gw + 1];
    float a0[8] = {0.f,0.f,0.f,0.f,0.f,0.f,0.f,0.f};
    float a1[8] = {0.f,0.f,0.f,0.f,0.f,0.f,0.f,0.f};
    for (int base = beg; base < end; base += 64) {
        int cnt = end - base; if (cnt > 64) cnt = 64;
        int sidx = (lane < cnt) ? csr[base + lane] : 0;
        int j = grp;
        for (; j + 4 < cnt; j += 8) {
            int s0 = __shfl(sidx, j, 64);
            int s1 = __shfl(sidx, j + 4, 64);
            s16x8 v0 = *(const s16x8*)(hin + (s0 << 7) + coff);
            s16x8 v1 = *(const s16x8*)(hin + (s1 << 7) + coff);
            #pragma unroll
            for (int q = 0; q < 8; ++q) {
                a0[q] += h2f((ushort)v0[q]);
                a1[q] += h2f((ushort)v1[q]);
            }
        }
        if (j < cnt) {
            int s0 = __shfl(sidx, j, 64);
            s16x8 v0 = *(const s16x8*)(hin + (s0 << 7) + coff);
            #pragma unroll
            for (int q = 0; q < 8; ++q) a0[q] += h2f((ushort)v0[q]);
        }
    }
    #pragma unroll
    for (int q = 0; q < 8; ++q) {
        float t = a0[q] + a1[q];
        t += __shfl_xor(t, 16, 64);
        t += __shfl_xor(t, 32, 64);
        a0[q] = t;
    }
    if (grp == 0) {
        s16x8 sv = *(const s16x8*)(hin + (gw << 7) + coff);
        float dn = dinv[gw];
        float* orow = hout + (gw << 7) + coff;
        float o[8];
        #pragma unroll
        for (int q = 0; q < 8; ++q)
            o[q] = (a0[q] + h2f((ushort)sv[q])) * dn;
        *(float4*)(orow)     = make_float4(o[0], o[1], o[2], o[3]);
        *(float4*)(orow + 4) = make_float4(o[4], o[5], o[6], o[7]);
    }
}

// ------------------------------------------------------------------ MFMA GEMM (M x 128 @ 128 x 128)
// A is FP32; split into bf16 hi+lo at staging; 2 chained MFMAs -> fp24-accurate A.
// C = prelu(A@B + bias, alpha); Ch (fp16 table) = C * dinv[row]
// MODE 1 additionally writes fp32 C to Cf (hgcn output)
template<int MODE>
__global__ __launch_bounds__(256)
void gemm12(const float* __restrict__ A, const ushort* __restrict__ Bt,
            const float* __restrict__ bias, const float* __restrict__ alpha,
            const float* __restrict__ dinv,
            float* __restrict__ Cf, ushort* __restrict__ Ch, int nrows) {
    __shared__ char Ah[32768];
    __shared__ char Al[32768];
    __shared__ char Bs[32768];
    int tid = threadIdx.x;
    int row0 = blockIdx.x * 128;
    #pragma unroll
    for (int it = 0; it < 8; ++it) {
        int idx = tid + it * 256;
        int r = idx >> 4, cb = (idx & 15) << 4;
        int sw = cb ^ ((r & 15) << 4);
        int row = row0 + r;
        float vv[8] = {0.f,0.f,0.f,0.f,0.f,0.f,0.f,0.f};
        if (row < nrows) {
            const float* src = A + (size_t)row * 128 + ((idx & 15) << 3);
            float4 v0 = *(const float4*)(src);
            float4 v1 = *(const float4*)(src + 4);
            vv[0]=v0.x; vv[1]=v0.y; vv[2]=v0.z; vv[3]=v0.w;
            vv[4]=v1.x; vv[5]=v1.y; vv[6]=v1.z; vv[7]=v1.w;
        }
        ushort hi[8], lo[8];
        #pragma unroll
        for (int q = 0; q < 8; ++q) {
            ushort h = f2b(vv[q]);
            hi[q] = h;
            lo[q] = f2b(vv[q] - b2f(h));
        }
        *(uint4*)(Ah + r * 256 + sw) = *(uint4*)hi;
        *(uint4*)(Al + r * 256 + sw) = *(uint4*)lo;
        uint4 bv = *(const uint4*)((const char*)Bt + (size_t)idx * 16);
        *(uint4*)(Bs + r * 256 + sw) = bv;
    }
    __syncthreads();

    int w = tid >> 6, lane = tid & 63;
    int bq = lane >> 4, tr = lane & 15;
    f32x4 acc[2][8];
    #pragma unroll
    for (int mi = 0; mi < 2; ++mi)
        #pragma unroll
        for (int nj = 0; nj < 8; ++nj)
            acc[mi][nj] = (f32x4){0.f, 0.f, 0.f, 0.f};

    #pragma unroll
    for (int s = 0; s < 4; ++s) {
        int xoff = (s * 64 + bq * 16) ^ ((tr & 15) << 4);
        s16x8 ah[2], al[2], bfr[8];
        #pragma unroll
        for (int mi = 0; mi < 2; ++mi) {
            ah[mi] = *(const s16x8*)(Ah + (w * 32 + mi * 16 + tr) * 256 + xoff);
            al[mi] = *(const s16x8*)(Al + (w * 32 + mi * 16 + tr) * 256 + xoff);
        }
        #pragma unroll
        for (int nj = 0; nj < 8; ++nj)
            bfr[nj] = *(const s16x8*)(Bs + (nj * 16 + tr) * 256 + xoff);
        #pragma unroll
        for (int mi = 0; mi < 2; ++mi)
            #pragma unroll
            for (int nj = 0; nj < 8; ++nj) {
                acc[mi][nj] = __builtin_amdgcn_mfma_f32_16x16x32_bf16(ah[mi], bfr[nj], acc[mi][nj], 0, 0, 0);
                acc[mi][nj] = __builtin_amdgcn_mfma_f32_16x16x32_bf16(al[mi], bfr[nj], acc[mi][nj], 0, 0, 0);
            }
    }

    int g = lane >> 4, c = lane & 15;
    float aval = alpha[0];
    float bb[8];
    #pragma unroll
    for (int nj = 0; nj < 8; ++nj) bb[nj] = bias[nj * 16 + c];
    #pragma unroll
    for (int mi = 0; mi < 2; ++mi) {
        #pragma unroll
        for (int j = 0; j < 4; ++j) {
            int row = row0 + w * 32 + mi * 16 + g * 4 + j;
            if (row >= nrows) continue;
            float dv = dinv[row];
            #pragma unroll
            for (int nj = 0; nj < 8; ++nj) {
                int col = nj * 16 + c;
                float t = acc[mi][nj][j] + bb[nj];
                t = t >= 0.f ? t : aval * t;
                if (MODE) Cf[(size_t)row * 128 + col] = t;
                Ch[(size_t)row * 128 + col] = f2h(t * dv);
            }
        }
    }
}

// ------------------------------------------------------------------ mu/lv GEMM (+ fused hk, r)
// A (p) is FP32, hi/lo split; blockIdx.x = k; Bt3[k]: cols 0-63 mu, 64-127 lv
template<int FUSED>
__global__ __launch_bounds__(256)
void gemm3(const float* __restrict__ A, const ushort* __restrict__ Bt3,
           const float* __restrict__ bmu, const float* __restrict__ blv,
           const float* __restrict__ amu, const float* __restrict__ alv,
           const float* __restrict__ Wr, const float* __restrict__ br,
           const float* __restrict__ eps,
           float* __restrict__ out_mu, float* __restrict__ out_lv,
           float* __restrict__ out_hk, float* __restrict__ out_r, int nrows) {
    __shared__ char Ah[32768];
    __shared__ char Al[32768];
    __shared__ char Bs[32768];
    int tid = threadIdx.x;
    int k = blockIdx.x;
    int row0 = blockIdx.y * 128;
    const ushort* Bt = Bt3 + (size_t)k * 16384;
    #pragma unroll
    for (int it = 0; it < 8; ++it) {
        int idx = tid + it * 256;
        int r = idx >> 4, cb = (idx & 15) << 4;
        int sw = cb ^ ((r & 15) << 4);
        int row = row0 + r;
        float vv[8] = {0.f,0.f,0.f,0.f,0.f,0.f,0.f,0.f};
        if (row < nrows) {
            const float* src = A + (size_t)row * 128 + ((idx & 15) << 3);
            float4 v0 = *(const float4*)(src);
            float4 v1 = *(const float4*)(src + 4);
            vv[0]=v0.x; vv[1]=v0.y; vv[2]=v0.z; vv[3]=v0.w;
            vv[4]=v1.x; vv[5]=v1.y; vv[6]=v1.z; vv[7]=v1.w;
        }
        ushort hi[8], lo[8];
        #pragma unroll
        for (int q = 0; q < 8; ++q) {
            ushort h = f2b(vv[q]);
            hi[q] = h;
            lo[q] = f2b(vv[q] - b2f(h));
        }
        *(uint4*)(Ah + r * 256 + sw) = *(uint4*)hi;
        *(uint4*)(Al + r * 256 + sw) = *(uint4*)lo;
        uint4 bv = *(const uint4*)((const char*)Bt + (size_t)idx * 16);
        *(uint4*)(Bs + r * 256 + sw) = bv;
    }
    __syncthreads();

    int w = tid >> 6, lane = tid & 63;
    int bq = lane >> 4, tr = lane & 15;
    f32x4 acc[2][8];
    #pragma unroll
    for (int mi = 0; mi < 2; ++mi)
        #pragma unroll
        for (int nj = 0; nj < 8; ++nj)
            acc[mi][nj] = (f32x4){0.f, 0.f, 0.f, 0.f};

    #pragma unroll
    for (int s = 0; s < 4; ++s) {
        int xoff = (s * 64 + bq * 16) ^ ((tr & 15) << 4);
        s16x8 ah[2], al[2], bfr[8];
        #pragma unroll
        for (int mi = 0; mi < 2; ++mi) {
            ah[mi] = *(const s16x8*)(Ah + (w * 32 + mi * 16 + tr) * 256 + xoff);
            al[mi] = *(const s16x8*)(Al + (w * 32 + mi * 16 + tr) * 256 + xoff);
        }
        #pragma unroll
        for (int nj = 0; nj < 8; ++nj)
            bfr[nj] = *(const s16x8*)(Bs + (nj * 16 + tr) * 256 + xoff);
        #pragma unroll
        for (int mi = 0; mi < 2; ++mi)
            #pragma unroll
            for (int nj = 0; nj < 8; ++nj) {
                acc[mi][nj] = __builtin_amdgcn_mfma_f32_16x16x32_bf16(ah[mi], bfr[nj], acc[mi][nj], 0, 0, 0);
                acc[mi][nj] = __builtin_amdgcn_mfma_f32_16x16x32_bf16(al[mi], bfr[nj], acc[mi][nj], 0, 0, 0);
            }
    }

    int g = lane >> 4, c = lane & 15;
    float amuv = amu[k], alvv = alv[k];
    float brk = br[k];
    float bmv[4], blvb[4], wrv[4];
    #pragma unroll
    for (int nj = 0; nj < 4; ++nj) {
        int d = nj * 16 + c;
        bmv[nj] = bmu[k * 64 + d];
        blvb[nj] = blv[k * 64 + d];
        wrv[nj] = FUSED ? Wr[k * 64 + d] : 0.f;
    }
    #pragma unroll
    for (int mi = 0; mi < 2; ++mi) {
        float rsum[4] = {0.f, 0.f, 0.f, 0.f};
        #pragma unroll
        for (int j = 0; j < 4; ++j) {
            int row = row0 + w * 32 + mi * 16 + g * 4 + j;
            if (row >= nrows) continue;
            #pragma unroll
            for (int nj = 0; nj < 4; ++nj) {
                int d = nj * 16 + c;
                size_t oc = (size_t)row * KD + k * 64 + d;
                float m_ = acc[mi][nj][j] + bmv[nj];
                m_ = m_ >= 0.f ? m_ : amuv * m_;
                float l_ = acc[mi][nj + 4][j] + blvb[nj];
                l_ = l_ >= 0.f ? l_ : alvv * l_;
                l_ = 1.f / (1.f + __expf(-l_));
                out_mu[oc] = m_;
                out_lv[oc] = l_;
                if (FUSED) {
                    float h = fmaf(eps[oc], __expf(0.5f * l_), m_);
                    out_hk[oc] = h;
                    rsum[j] = fmaf(h, wrv[nj], rsum[j]);
                }
            }
        }
        if (FUSED) {
            #pragma unroll
            for (int j = 0; j < 4; ++j) {
                float t = rsum[j];
                t += __shfl_xor(t, 1, 64);
                t += __shfl_xor(t, 2, 64);
                t += __shfl_xor(t, 4, 64);
                t += __shfl_xor(t, 8, 64);
                if (c == 0) {
                    int row = row0 + w * 32 + mi * 16 + g * 4 + j;
                    if (row < nrows)
                        out_r[(size_t)row * 4 + k] = 1.f / (1.f + __expf(-(t + brk)));
                }
            }
        }
    }
}

// ------------------------------------------------------------------ fallback reparam + r
__global__ void hk_kernel(const float* __restrict__ mu, const float* __restrict__ lv,
                          const float* __restrict__ eps, const float* __restrict__ Wr,
                          const float* __restrict__ br, float* __restrict__ hk,
                          float* __restrict__ r, int n) {
    int gw = (blockIdx.x * blockDim.x + threadIdx.x) >> 6;
    int lane = threadIdx.x & 63;
    if (gw >= n) return;
    size_t base = (size_t)gw * KD;
    #pragma unroll
    for (int k = 0; k < 4; ++k) {
        int c = k * 64 + lane;
        float m = mu[base + c], v = lv[base + c], e = eps[base + c];
        float h = fmaf(e, __expf(0.5f * v), m);
        hk[base + c] = h;
        float t = h * Wr[k * 64 + lane];
        #pragma unroll
        for (int off = 32; off >= 1; off >>= 1) t += __shfl_xor(t, off, 64);
        if (lane == 0) r[(size_t)gw * 4 + k] = 1.f / (1.f + __expf(-(t + br[k])));
    }
}

// ------------------------------------------------------------------ launch
extern "C" void kernel_launch(void* const* d_in, const int* in_sizes, int n_in,
                              void* d_out, int out_size, void* d_ws, size_t ws_size,
                              hipStream_t stream) {
    const float* x   = (const float*)d_in[0];
    const int*   ei  = (const int*)d_in[1];
    const float* W1  = (const float*)d_in[2];
    const float* b1  = (const float*)d_in[3];
    const float* a1  = (const float*)d_in[4];
    const float* W2  = (const float*)d_in[5];
    const float* b2  = (const float*)d_in[6];
    const float* a2  = (const float*)d_in[7];
    const float* Wmu = (const float*)d_in[8];
    const float* bmu = (const float*)d_in[9];
    const float* amu = (const float*)d_in[10];
    const float* Wlv = (const float*)d_in[11];
    const float* blv = (const float*)d_in[12];
    const float* alv = (const float*)d_in[13];
    const float* Wr  = (const float*)d_in[14];
    const float* br  = (const float*)d_in[15];
    const float* eps = (const float*)d_in[16];

    float* out      = (float*)d_out;
    float* out_hgcn = out;                                  // N*128
    float* out_lv   = out + (size_t)N_NODES * HDIM;         // N*256
    float* out_mu   = out_lv + (size_t)N_NODES * KD;        // N*256
    float* out_hk   = out_mu + (size_t)N_NODES * KD;        // N*256
    float* out_r    = out_hk + (size_t)N_NODES * KD;        // N*4

    char* ws = (char*)d_ws;
    int*    cnt      = (int*)ws;                       // N ints
    int*    offsets  = (int*)(ws + 204800);            // N+1 ints
    int*    cursor   = (int*)(ws + 409600);            // N ints
    int*    csr      = (int*)(ws + 614400);            // E ints
    float*  dinv     = (float*)(ws + 3814400);         // N floats
    ushort* w1t      = (ushort*)(ws + 4014592);        // 16384 bf16
    ushort* w2t      = (ushort*)(ws + 4047360);        // 16384 bf16
    ushort* bt3      = (ushort*)(ws + 4080128);        // 65536 bf16 (ends 4211200)
    int*    blocksum = (int*)(ws + 4211200);           // 49 ints
    int*    blockpref= (int*)(ws + 4211456);           // 49 ints

    // fp16 gather tables in the hk output region (fully rewritten at the end)
    ushort* X16 = (ushort*)out_hk;                      // bytes [0, 12.8M)
    ushort* H16 = X16 + (size_t)N_NODES * HDIM;         // [12.8M, 25.6M)
    ushort* G16 = H16 + (size_t)N_NODES * HDIM;         // [25.6M, 38.4M)

    // fp32 prop outputs: q1 in out_mu region, q2 in out_lv region (dead until gemm3)
    float* q1 = out_mu;
    float* q2 = out_lv;

    // p (fp32, 25.6MB): ws if it fits, else hk bytes [0, 25.6M) (X16/H16 dead by then)
    const size_t P_OFF = 4211712;
    const bool fused = ws_size >= P_OFF + (size_t)N_NODES * HDIM * 4;
    float* P = fused ? (float*)(ws + P_OFF) : (float*)out_hk;

    const int* e_src = ei;
    const int* e_dst = ei + N_EDGES;
    const int NB = (N_NODES + 1023) / 1024;   // 49

    zero_int <<<(N_NODES + 255) / 256, 256, 0, stream>>>(cnt, N_NODES);
    count_deg<<<(N_EDGES + 255) / 256, 256, 0, stream>>>(e_dst, cnt, N_EDGES);
    calc_dinv<<<(N_NODES + 255) / 256, 256, 0, stream>>>(cnt, dinv, N_NODES);
    scan_blk <<<NB, 1024, 0, stream>>>(cnt, offsets, blocksum, N_NODES);
    scan_top <<<1, 64, 0, stream>>>(blocksum, blockpref, offsets, NB, N_NODES);
    scan_add <<<NB, 1024, 0, stream>>>(offsets, cursor, blockpref, N_NODES);
    fill_csr <<<(N_EDGES + 255) / 256, 256, 0, stream>>>(e_src, e_dst, cursor, csr, N_EDGES);
    sort_csr <<<(N_NODES + 255) / 256, 256, 0, stream>>>(csr, offsets, N_NODES);

    prep_w<<<384, 256, 0, stream>>>(W1, W2, Wmu, Wlv, w1t, w2t, bt3);
    conv_x<<<(N_NODES * 32 + 255) / 256, 256, 0, stream>>>((const float4*)x, (ushort4*)X16, dinv, N_NODES * 32);

    // q1 = prop(x*dinv)            X16 -> q1 (fp32)
    prop_b<<<12500, 256, 0, stream>>>(X16, q1, csr, offsets, dinv, N_NODES);
    // h = prelu(q1@W1+b1); H16 = fp16(h*dinv)
    gemm12<0><<<391, 256, 0, stream>>>(q1, w1t, b1, a1, dinv, nullptr, H16, N_NODES);
    // q2 = prop(h*dinv)            H16 -> q2 (fp32)
    prop_b<<<12500, 256, 0, stream>>>(H16, q2, csr, offsets, dinv, N_NODES);
    // hgcn = prelu(q2@W2+b2) fp32 -> out; G16 = fp16(hgcn*dinv)
    gemm12<1><<<391, 256, 0, stream>>>(q2, w2t, b2, a2, dinv, out_hgcn, G16, N_NODES);
    // p = prop(hgcn*dinv)          G16 -> P (fp32)
    prop_b<<<12500, 256, 0, stream>>>(G16, P, csr, offsets, dinv, N_NODES);

    dim3 g3(4, 391);
    if (fused) {
        gemm3<1><<<g3, 256, 0, stream>>>(P, bt3, bmu, blv, amu, alv, Wr, br, eps,
                                         out_mu, out_lv, out_hk, out_r, N_NODES);
    } else {
        gemm3<0><<<g3, 256, 0, stream>>>(P, bt3, bmu, blv, amu, alv, Wr, br, eps,
                                         out_mu, out_lv, out_hk, out_r, N_NODES);
        hk_kernel<<<12500, 256, 0, stream>>>(out_mu, out_lv, eps, Wr, br, out_hk, out_r, N_NODES);
    }
}

// Round 9
// 393.014 us; speedup vs baseline: 1.1090x; 1.1090x over previous
//
#include <hip/hip_runtime.h>
#include <math.h>

#define N_NODES 50000
#define N_EDGES 800000
#define HDIM 128
#define KD 256   // K*D

typedef float f32x4 __attribute__((ext_vector_type(4)));
typedef short s16x8 __attribute__((ext_vector_type(8)));

__device__ __forceinline__ ushort f2b(float f) {        // fp32 -> bf16 RNE
    union { float f; unsigned u; } x; x.f = f;
    unsigned u = x.u;
    return (ushort)((u + 0x7FFF + ((u >> 16) & 1)) >> 16);
}
__device__ __forceinline__ float b2f(ushort h) {
    union { unsigned u; float f; } x; x.u = ((unsigned)h) << 16; return x.f;
}
__device__ __forceinline__ ushort f2h(float f) {        // fp32 -> fp16 RNE
    union { _Float16 h; ushort u; } x; x.h = (_Float16)f; return x.u;
}
__device__ __forceinline__ float h2f(ushort u) {
    union { ushort u; _Float16 h; } x; x.u = u; return (float)x.h;
}

// ------------------------------------------------------------------ CSR build
__global__ void zero_int(int* __restrict__ p, int n) {
    int i = blockIdx.x * blockDim.x + threadIdx.x;
    if (i < n) p[i] = 0;
}

__global__ void count_deg(const int* __restrict__ dst, int* __restrict__ cnt, int e) {
    int i = blockIdx.x * blockDim.x + threadIdx.x;
    if (i < e) atomicAdd(&cnt[dst[i]], 1);
}

__global__ void calc_dinv(const int* __restrict__ cnt, float* __restrict__ dinv, int n) {
    int i = blockIdx.x * blockDim.x + threadIdx.x;
    if (i < n) dinv[i] = rsqrtf((float)(cnt[i] + 1));
}

__global__ __launch_bounds__(1024)
void scan_blk(const int* __restrict__ cnt, int* __restrict__ offsets,
              int* __restrict__ blocksum, int n) {
    __shared__ int wsum[16];
    int tid = threadIdx.x;
    int i = blockIdx.x * 1024 + tid;
    int lane = tid & 63, wid = tid >> 6;
    int v = (i < n) ? cnt[i] : 0;
    int x = v;
    #pragma unroll
    for (int off = 1; off < 64; off <<= 1) {
        int t = __shfl_up(x, off, 64);
        if (lane >= off) x += t;
    }
    if (lane == 63) wsum[wid] = x;
    __syncthreads();
    if (wid == 0) {
        int w = (lane < 16) ? wsum[lane] : 0;
        #pragma unroll
        for (int off = 1; off < 16; off <<= 1) {
            int t = __shfl_up(w, off, 64);
            if (lane >= off) w += t;
        }
        if (lane < 16) wsum[lane] = w;
    }
    __syncthreads();
    int waveoff = (wid > 0) ? wsum[wid - 1] : 0;
    if (i < n) offsets[i] = x + waveoff - v;
    if (tid == 1023) blocksum[blockIdx.x] = x + waveoff;
}

__global__ void scan_top(const int* __restrict__ blocksum, int* __restrict__ blockpref,
                         int* __restrict__ offsets, int nb, int n) {
    int lane = threadIdx.x;
    int v = (lane < nb) ? blocksum[lane] : 0;
    int x = v;
    #pragma unroll
    for (int off = 1; off < 64; off <<= 1) {
        int t = __shfl_up(x, off, 64);
        if (lane >= off) x += t;
    }
    if (lane < nb) blockpref[lane] = x - v;
    if (lane == 63) offsets[n] = x;
}

__global__ __launch_bounds__(1024)
void scan_add(int* __restrict__ offsets, int* __restrict__ cursor,
              const int* __restrict__ blockpref, int n) {
    int i = blockIdx.x * 1024 + threadIdx.x;
    if (i < n) {
        int o = offsets[i] + blockpref[blockIdx.x];
        offsets[i] = o;
        cursor[i] = o;
    }
}

__global__ void fill_csr(const int* __restrict__ src, const int* __restrict__ dst,
                         int* __restrict__ cursor, int* __restrict__ csr, int e) {
    int i = blockIdx.x * blockDim.x + threadIdx.x;
    if (i < e) {
        int d = dst[i];
        int pos = atomicAdd(&cursor[d], 1);
        csr[pos] = src[i];
    }
}

// deterministic edge order per node (atomics scramble it run-to-run)
__global__ void sort_csr(int* __restrict__ csr, const int* __restrict__ offsets, int n) {
    int node = blockIdx.x * 256 + threadIdx.x;
    if (node >= n) return;
    int beg = offsets[node], end = offsets[node + 1];
    for (int i = beg + 1; i < end; ++i) {
        int key = csr[i];
        int j = i - 1;
        while (j >= beg && csr[j] > key) { csr[j + 1] = csr[j]; --j; }
        csr[j + 1] = key;
    }
}

// ------------------------------------------------------------------ prep
// x (fp32) -> fp16 gather table, pre-scaled by dinv[row]
__global__ void conv_x(const float4* __restrict__ x, ushort4* __restrict__ o,
                       const float* __restrict__ dinv, int n4) {
    int i = blockIdx.x * 256 + threadIdx.x;
    if (i >= n4) return;
    int row = i >> 5;
    float dv = dinv[row];
    float4 v = x[i];
    ushort4 u;
    u.x = f2h(v.x * dv); u.y = f2h(v.y * dv);
    u.z = f2h(v.z * dv); u.w = f2h(v.w * dv);
    o[i] = u;
}

// weights -> bf16 transposed: W1T[n][k], W2T[n][k], Bt3[k][n(mu|lv)][h]
__global__ void prep_w(const float* __restrict__ W1, const float* __restrict__ W2,
                       const float* __restrict__ Wmu, const float* __restrict__ Wlv,
                       ushort* __restrict__ w1t, ushort* __restrict__ w2t,
                       ushort* __restrict__ bt3) {
    int i = blockIdx.x * 256 + threadIdx.x;
    if (i < 16384) {
        int nn = i >> 7, k = i & 127;
        w1t[i] = f2b(W1[k * 128 + nn]);
    } else if (i < 32768) {
        int j = i - 16384; int nn = j >> 7, k = j & 127;
        w2t[j] = f2b(W2[k * 128 + nn]);
    } else if (i < 98304) {
        int j = i - 32768;                 // ((k*128 + n)*128 + h)
        int h = j & 127; int nk = j >> 7; int nn = nk & 127; int k = nk >> 7;
        float v = (nn < 64) ? Wmu[k * 8192 + h * 64 + nn]
                            : Wlv[k * 8192 + h * 64 + (nn - 64)];
        bt3[j] = f2b(v);
    }
}

// ------------------------------------------------------------------ propagate
// reads fp16 table (rows pre-scaled by dinv[src]):
// out[i] = dinv[i] * (sum_nbr tab[s] + tab[i])
// O16=0: write fp32 (feeds hi/lo GEMM); O16=1: write bf16 (feeds gemm3)
// FROZEN STRUCTURE: 2-deep chains (4-deep variants mis-validate; see R5-R7).
template<int O16>
__global__ __launch_bounds__(256)
void prop_b(const ushort* __restrict__ hin, float* __restrict__ hout32,
            ushort* __restrict__ hout16,
            const int* __restrict__ csr, const int* __restrict__ offsets,
            const float* __restrict__ dinv, int n) {
    int gw = blockIdx.x * 4 + (threadIdx.x >> 6);
    if (gw >= n) return;
    int lane = threadIdx.x & 63;
    int grp = lane >> 4, gl = lane & 15;
    int coff = gl << 3;               // element offset within row
    int beg = offsets[gw], end = offsets[gw + 1];
    float a0[8] = {0.f,0.f,0.f,0.f,0.f,0.f,0.f,0.f};
    float a1[8] = {0.f,0.f,0.f,0.f,0.f,0.f,0.f,0.f};
    for (int base = beg; base < end; base += 64) {
        int cnt = end - base; if (cnt > 64) cnt = 64;
        int sidx = (lane < cnt) ? csr[base + lane] : 0;
        int j = grp;
        for (; j + 4 < cnt; j += 8) {
            int s0 = __shfl(sidx, j, 64);
            int s1 = __shfl(sidx, j + 4, 64);
            s16x8 v0 = *(const s16x8*)(hin + (s0 << 7) + coff);
            s16x8 v1 = *(const s16x8*)(hin + (s1 << 7) + coff);
            #pragma unroll
            for (int q = 0; q < 8; ++q) {
                a0[q] += h2f((ushort)v0[q]);
                a1[q] += h2f((ushort)v1[q]);
            }
        }
        if (j < cnt) {
            int s0 = __shfl(sidx, j, 64);
            s16x8 v0 = *(const s16x8*)(hin + (s0 << 7) + coff);
            #pragma unroll
            for (int q = 0; q < 8; ++q) a0[q] += h2f((ushort)v0[q]);
        }
    }
    #pragma unroll
    for (int q = 0; q < 8; ++q) {
        float t = a0[q] + a1[q];
        t += __shfl_xor(t, 16, 64);
        t += __shfl_xor(t, 32, 64);
        a0[q] = t;
    }
    if (grp == 0) {
        s16x8 sv = *(const s16x8*)(hin + (gw << 7) + coff);
        float dn = dinv[gw];
        float o[8];
        #pragma unroll
        for (int q = 0; q < 8; ++q)
            o[q] = (a0[q] + h2f((ushort)sv[q])) * dn;
        if (O16) {
            s16x8 ob;
            #pragma unroll
            for (int q = 0; q < 8; ++q) ob[q] = (short)f2b(o[q]);
            *(s16x8*)(hout16 + (gw << 7) + coff) = ob;
        } else {
            float* orow = hout32 + (gw << 7) + coff;
            *(float4*)(orow)     = make_float4(o[0], o[1], o[2], o[3]);
            *(float4*)(orow + 4) = make_float4(o[4], o[5], o[6], o[7]);
        }
    }
}

// ------------------------------------------------------------------ MFMA GEMM (M x 128 @ 128 x 128)
// A is FP32; split into bf16 hi+lo at staging; 2 chained MFMAs -> fp24-accurate A.
// (hi/lo needed here: error cascades into the hgcn output chain)
// C = prelu(A@B + bias, alpha); Ch (fp16 table) = C * dinv[row]
// MODE 1 additionally writes fp32 C to Cf (hgcn output)
template<int MODE>
__global__ __launch_bounds__(256)
void gemm12(const float* __restrict__ A, const ushort* __restrict__ Bt,
            const float* __restrict__ bias, const float* __restrict__ alpha,
            const float* __restrict__ dinv,
            float* __restrict__ Cf, ushort* __restrict__ Ch, int nrows) {
    __shared__ char Ah[32768];
    __shared__ char Al[32768];
    __shared__ char Bs[32768];
    int tid = threadIdx.x;
    int row0 = blockIdx.x * 128;
    #pragma unroll
    for (int it = 0; it < 8; ++it) {
        int idx = tid + it * 256;
        int r = idx >> 4, cb = (idx & 15) << 4;
        int sw = cb ^ ((r & 15) << 4);
        int row = row0 + r;
        float vv[8] = {0.f,0.f,0.f,0.f,0.f,0.f,0.f,0.f};
        if (row < nrows) {
            const float* src = A + (size_t)row * 128 + ((idx & 15) << 3);
            float4 v0 = *(const float4*)(src);
            float4 v1 = *(const float4*)(src + 4);
            vv[0]=v0.x; vv[1]=v0.y; vv[2]=v0.z; vv[3]=v0.w;
            vv[4]=v1.x; vv[5]=v1.y; vv[6]=v1.z; vv[7]=v1.w;
        }
        ushort hi[8], lo[8];
        #pragma unroll
        for (int q = 0; q < 8; ++q) {
            ushort h = f2b(vv[q]);
            hi[q] = h;
            lo[q] = f2b(vv[q] - b2f(h));
        }
        *(uint4*)(Ah + r * 256 + sw) = *(uint4*)hi;
        *(uint4*)(Al + r * 256 + sw) = *(uint4*)lo;
        uint4 bv = *(const uint4*)((const char*)Bt + (size_t)idx * 16);
        *(uint4*)(Bs + r * 256 + sw) = bv;
    }
    __syncthreads();

    int w = tid >> 6, lane = tid & 63;
    int bq = lane >> 4, tr = lane & 15;
    f32x4 acc[2][8];
    #pragma unroll
    for (int mi = 0; mi < 2; ++mi)
        #pragma unroll
        for (int nj = 0; nj < 8; ++nj)
            acc[mi][nj] = (f32x4){0.f, 0.f, 0.f, 0.f};

    #pragma unroll
    for (int s = 0; s < 4; ++s) {
        int xoff = (s * 64 + bq * 16) ^ ((tr & 15) << 4);
        s16x8 ah[2], al[2], bfr[8];
        #pragma unroll
        for (int mi = 0; mi < 2; ++mi) {
            ah[mi] = *(const s16x8*)(Ah + (w * 32 + mi * 16 + tr) * 256 + xoff);
            al[mi] = *(const s16x8*)(Al + (w * 32 + mi * 16 + tr) * 256 + xoff);
        }
        #pragma unroll
        for (int nj = 0; nj < 8; ++nj)
            bfr[nj] = *(const s16x8*)(Bs + (nj * 16 + tr) * 256 + xoff);
        #pragma unroll
        for (int mi = 0; mi < 2; ++mi)
            #pragma unroll
            for (int nj = 0; nj < 8; ++nj) {
                acc[mi][nj] = __builtin_amdgcn_mfma_f32_16x16x32_bf16(ah[mi], bfr[nj], acc[mi][nj], 0, 0, 0);
                acc[mi][nj] = __builtin_amdgcn_mfma_f32_16x16x32_bf16(al[mi], bfr[nj], acc[mi][nj], 0, 0, 0);
            }
    }

    int g = lane >> 4, c = lane & 15;
    float aval = alpha[0];
    float bb[8];
    #pragma unroll
    for (int nj = 0; nj < 8; ++nj) bb[nj] = bias[nj * 16 + c];
    #pragma unroll
    for (int mi = 0; mi < 2; ++mi) {
        #pragma unroll
        for (int j = 0; j < 4; ++j) {
            int row = row0 + w * 32 + mi * 16 + g * 4 + j;
            if (row >= nrows) continue;
            float dv = dinv[row];
            #pragma unroll
            for (int nj = 0; nj < 8; ++nj) {
                int col = nj * 16 + c;
                float t = acc[mi][nj][j] + bb[nj];
                t = t >= 0.f ? t : aval * t;
                if (MODE) Cf[(size_t)row * 128 + col] = t;
                Ch[(size_t)row * 128 + col] = f2h(t * dv);
            }
        }
    }
}

// ------------------------------------------------------------------ mu/lv GEMM (+ fused hk, r)
// A (p) is bf16 (mu/lv/hk/r chain tolerated bf16-A in R1-R4); single MFMA,
// 64 KB LDS -> 2 blocks/CU. blockIdx.x = k; Bt3[k]: cols 0-63 mu, 64-127 lv
template<int FUSED>
__global__ __launch_bounds__(256)
void gemm3(const ushort* __restrict__ A, const ushort* __restrict__ Bt3,
           const float* __restrict__ bmu, const float* __restrict__ blv,
           const float* __restrict__ amu, const float* __restrict__ alv,
           const float* __restrict__ Wr, const float* __restrict__ br,
           const float* __restrict__ eps,
           float* __restrict__ out_mu, float* __restrict__ out_lv,
           float* __restrict__ out_hk, float* __restrict__ out_r, int nrows) {
    __shared__ char As[32768];
    __shared__ char Bs[32768];
    int tid = threadIdx.x;
    int k = blockIdx.x;
    int row0 = blockIdx.y * 128;
    const ushort* Bt = Bt3 + (size_t)k * 16384;
    #pragma unroll
    for (int it = 0; it < 8; ++it) {
        int idx = tid + it * 256;
        int r = idx >> 4, cb = (idx & 15) << 4;
        int sw = cb ^ ((r & 15) << 4);
        uint4 v = make_uint4(0, 0, 0, 0);
        int row = row0 + r;
        if (row < nrows) v = *(const uint4*)((const char*)A + (size_t)row * 256 + cb);
        *(uint4*)(As + r * 256 + sw) = v;
        uint4 bv = *(const uint4*)((const char*)Bt + (size_t)idx * 16);
        *(uint4*)(Bs + r * 256 + sw) = bv;
    }
    __syncthreads();

    int w = tid >> 6, lane = tid & 63;
    int bq = lane >> 4, tr = lane & 15;
    f32x4 acc[2][8];
    #pragma unroll
    for (int mi = 0; mi < 2; ++mi)
        #pragma unroll
        for (int nj = 0; nj < 8; ++nj)
            acc[mi][nj] = (f32x4){0.f, 0.f, 0.f, 0.f};

    #pragma unroll
    for (int s = 0; s < 4; ++s) {
        int xoff = (s * 64 + bq * 16) ^ ((tr & 15) << 4);
        s16x8 af[2], bfr[8];
        #pragma unroll
        for (int mi = 0; mi < 2; ++mi)
            af[mi] = *(const s16x8*)(As + (w * 32 + mi * 16 + tr) * 256 + xoff);
        #pragma unroll
        for (int nj = 0; nj < 8; ++nj)
            bfr[nj] = *(const s16x8*)(Bs + (nj * 16 + tr) * 256 + xoff);
        #pragma unroll
        for (int mi = 0; mi < 2; ++mi)
            #pragma unroll
            for (int nj = 0; nj < 8; ++nj)
                acc[mi][nj] = __builtin_amdgcn_mfma_f32_16x16x32_bf16(af[mi], bfr[nj], acc[mi][nj], 0, 0, 0);
    }

    int g = lane >> 4, c = lane & 15;
    float amuv = amu[k], alvv = alv[k];
    float brk = br[k];
    float bmv[4], blvb[4], wrv[4];
    #pragma unroll
    for (int nj = 0; nj < 4; ++nj) {
        int d = nj * 16 + c;
        bmv[nj] = bmu[k * 64 + d];
        blvb[nj] = blv[k * 64 + d];
        wrv[nj] = FUSED ? Wr[k * 64 + d] : 0.f;
    }
    #pragma unroll
    for (int mi = 0; mi < 2; ++mi) {
        float rsum[4] = {0.f, 0.f, 0.f, 0.f};
        #pragma unroll
        for (int j = 0; j < 4; ++j) {
            int row = row0 + w * 32 + mi * 16 + g * 4 + j;
            if (row >= nrows) continue;
            #pragma unroll
            for (int nj = 0; nj < 4; ++nj) {
                int d = nj * 16 + c;
                size_t oc = (size_t)row * KD + k * 64 + d;
                float m_ = acc[mi][nj][j] + bmv[nj];
                m_ = m_ >= 0.f ? m_ : amuv * m_;
                float l_ = acc[mi][nj + 4][j] + blvb[nj];
                l_ = l_ >= 0.f ? l_ : alvv * l_;
                l_ = 1.f / (1.f + __expf(-l_));
                out_mu[oc] = m_;
                out_lv[oc] = l_;
                if (FUSED) {
                    float h = fmaf(eps[oc], __expf(0.5f * l_), m_);
                    out_hk[oc] = h;
                    rsum[j] = fmaf(h, wrv[nj], rsum[j]);
                }
            }
        }
        if (FUSED) {
            #pragma unroll
            for (int j = 0; j < 4; ++j) {
                float t = rsum[j];
                t += __shfl_xor(t, 1, 64);
                t += __shfl_xor(t, 2, 64);
                t += __shfl_xor(t, 4, 64);
                t += __shfl_xor(t, 8, 64);
                if (c == 0) {
                    int row = row0 + w * 32 + mi * 16 + g * 4 + j;
                    if (row < nrows)
                        out_r[(size_t)row * 4 + k] = 1.f / (1.f + __expf(-(t + brk)));
                }
            }
        }
    }
}

// ------------------------------------------------------------------ fallback reparam + r
__global__ void hk_kernel(const float* __restrict__ mu, const float* __restrict__ lv,
                          const float* __restrict__ eps, const float* __restrict__ Wr,
                          const float* __restrict__ br, float* __restrict__ hk,
                          float* __restrict__ r, int n) {
    int gw = (blockIdx.x * blockDim.x + threadIdx.x) >> 6;
    int lane = threadIdx.x & 63;
    if (gw >= n) return;
    size_t base = (size_t)gw * KD;
    #pragma unroll
    for (int k = 0; k < 4; ++k) {
        int c = k * 64 + lane;
        float m = mu[base + c], v = lv[base + c], e = eps[base + c];
        float h = fmaf(e, __expf(0.5f * v), m);
        hk[base + c] = h;
        float t = h * Wr[k * 64 + lane];
        #pragma unroll
        for (int off = 32; off >= 1; off >>= 1) t += __shfl_xor(t, off, 64);
        if (lane == 0) r[(size_t)gw * 4 + k] = 1.f / (1.f + __expf(-(t + br[k])));
    }
}

// ------------------------------------------------------------------ launch
extern "C" void kernel_launch(void* const* d_in, const int* in_sizes, int n_in,
                              void* d_out, int out_size, void* d_ws, size_t ws_size,
                              hipStream_t stream) {
    const float* x   = (const float*)d_in[0];
    const int*   ei  = (const int*)d_in[1];
    const float* W1  = (const float*)d_in[2];
    const float* b1  = (const float*)d_in[3];
    const float* a1  = (const float*)d_in[4];
    const float* W2  = (const float*)d_in[5];
    const float* b2  = (const float*)d_in[6];
    const float* a2  = (const float*)d_in[7];
    const float* Wmu = (const float*)d_in[8];
    const float* bmu = (const float*)d_in[9];
    const float* amu = (const float*)d_in[10];
    const float* Wlv = (const float*)d_in[11];
    const float* blv = (const float*)d_in[12];
    const float* alv = (const float*)d_in[13];
    const float* Wr  = (const float*)d_in[14];
    const float* br  = (const float*)d_in[15];
    const float* eps = (const float*)d_in[16];

    float* out      = (float*)d_out;
    float* out_hgcn = out;                                  // N*128
    float* out_lv   = out + (size_t)N_NODES * HDIM;         // N*256
    float* out_mu   = out_lv + (size_t)N_NODES * KD;        // N*256
    float* out_hk   = out_mu + (size_t)N_NODES * KD;        // N*256
    float* out_r    = out_hk + (size_t)N_NODES * KD;        // N*4

    char* ws = (char*)d_ws;
    int*    cnt      = (int*)ws;                       // N ints
    int*    offsets  = (int*)(ws + 204800);            // N+1 ints
    int*    cursor   = (int*)(ws + 409600);            // N ints
    int*    csr      = (int*)(ws + 614400);            // E ints
    float*  dinv     = (float*)(ws + 3814400);         // N floats
    ushort* w1t      = (ushort*)(ws + 4014592);        // 16384 bf16
    ushort* w2t      = (ushort*)(ws + 4047360);        // 16384 bf16
    ushort* bt3      = (ushort*)(ws + 4080128);        // 65536 bf16 (ends 4211200)
    int*    blocksum = (int*)(ws + 4211200);           // 49 ints
    int*    blockpref= (int*)(ws + 4211456);           // 49 ints

    // fp16 gather tables in the hk output region (fully rewritten at the end)
    ushort* X16 = (ushort*)out_hk;                      // bytes [0, 12.8M)
    ushort* H16 = X16 + (size_t)N_NODES * HDIM;         // [12.8M, 25.6M)
    ushort* G16 = H16 + (size_t)N_NODES * HDIM;         // [25.6M, 38.4M)

    // fp32 prop outputs: q1 in out_mu region, q2 in out_lv region (dead until gemm3)
    float* q1 = out_mu;
    float* q2 = out_lv;

    // P (bf16, 12.8MB): ws if it fits, else hk bytes [0,12.8M) (X16 dead by then)
    const size_t P_OFF = 4211712;
    const bool fused = ws_size >= P_OFF + (size_t)N_NODES * HDIM * 2;
    ushort* P = fused ? (ushort*)(ws + P_OFF) : X16;

    const int* e_src = ei;
    const int* e_dst = ei + N_EDGES;
    const int NB = (N_NODES + 1023) / 1024;   // 49

    zero_int <<<(N_NODES + 255) / 256, 256, 0, stream>>>(cnt, N_NODES);
    count_deg<<<(N_EDGES + 255) / 256, 256, 0, stream>>>(e_dst, cnt, N_EDGES);
    calc_dinv<<<(N_NODES + 255) / 256, 256, 0, stream>>>(cnt, dinv, N_NODES);
    scan_blk <<<NB, 1024, 0, stream>>>(cnt, offsets, blocksum, N_NODES);
    scan_top <<<1, 64, 0, stream>>>(blocksum, blockpref, offsets, NB, N_NODES);
    scan_add <<<NB, 1024, 0, stream>>>(offsets, cursor, blockpref, N_NODES);
    fill_csr <<<(N_EDGES + 255) / 256, 256, 0, stream>>>(e_src, e_dst, cursor, csr, N_EDGES);
    sort_csr <<<(N_NODES + 255) / 256, 256, 0, stream>>>(csr, offsets, N_NODES);

    prep_w<<<384, 256, 0, stream>>>(W1, W2, Wmu, Wlv, w1t, w2t, bt3);
    conv_x<<<(N_NODES * 32 + 255) / 256, 256, 0, stream>>>((const float4*)x, (ushort4*)X16, dinv, N_NODES * 32);

    // q1 = prop(x*dinv)            X16 -> q1 (fp32)
    prop_b<0><<<12500, 256, 0, stream>>>(X16, q1, nullptr, csr, offsets, dinv, N_NODES);
    // h = prelu(q1@W1+b1); H16 = fp16(h*dinv)
    gemm12<0><<<391, 256, 0, stream>>>(q1, w1t, b1, a1, dinv, nullptr, H16, N_NODES);
    // q2 = prop(h*dinv)            H16 -> q2 (fp32)
    prop_b<0><<<12500, 256, 0, stream>>>(H16, q2, nullptr, csr, offsets, dinv, N_NODES);
    // hgcn = prelu(q2@W2+b2) fp32 -> out; G16 = fp16(hgcn*dinv)
    gemm12<1><<<391, 256, 0, stream>>>(q2, w2t, b2, a2, dinv, out_hgcn, G16, N_NODES);
    // P = prop(hgcn*dinv)          G16 -> P (bf16)
    prop_b<1><<<12500, 256, 0, stream>>>(G16, nullptr, P, csr, offsets, dinv, N_NODES);

    dim3 g3(4, 391);
    if (fused) {
        gemm3<1><<<g3, 256, 0, stream>>>(P, bt3, bmu, blv, amu, alv, Wr, br, eps,
                                         out_mu, out_lv, out_hk, out_r, N_NODES);
    } else {
        gemm3<0><<<g3, 256, 0, stream>>>(P, bt3, bmu, blv, amu, alv, Wr, br, eps,
                                         out_mu, out_lv, out_hk, out_r, N_NODES);
        hk_kernel<<<12500, 256, 0, stream>>>(out_mu, out_lv, eps, Wr, br, out_hk, out_r, N_NODES);
    }
}

// Round 10
// 378.615 us; speedup vs baseline: 1.1512x; 1.0380x over previous
//
#include <hip/hip_runtime.h>
#include <math.h>

#define N_NODES 50000
#define N_EDGES 800000
#define HDIM 128
#define KD 256   // K*D

typedef float f32x4 __attribute__((ext_vector_type(4)));
typedef short s16x8 __attribute__((ext_vector_type(8)));

__device__ __forceinline__ ushort f2b(float f) {        // fp32 -> bf16 RNE
    union { float f; unsigned u; } x; x.f = f;
    unsigned u = x.u;
    return (ushort)((u + 0x7FFF + ((u >> 16) & 1)) >> 16);
}
__device__ __forceinline__ float b2f(ushort h) {
    union { unsigned u; float f; } x; x.u = ((unsigned)h) << 16; return x.f;
}
__device__ __forceinline__ ushort f2h(float f) {        // fp32 -> fp16 RNE
    union { _Float16 h; ushort u; } x; x.h = (_Float16)f; return x.u;
}
__device__ __forceinline__ float h2f(ushort u) {
    union { ushort u; _Float16 h; } x; x.u = u; return (float)x.h;
}

// ------------------------------------------------------------------ CSR build
__global__ void zero_int(int* __restrict__ p, int n) {
    int i = blockIdx.x * blockDim.x + threadIdx.x;
    if (i < n) p[i] = 0;
}

__global__ void count_deg(const int* __restrict__ dst, int* __restrict__ cnt, int e) {
    int i = blockIdx.x * blockDim.x + threadIdx.x;
    if (i < e) atomicAdd(&cnt[dst[i]], 1);
}

__global__ void calc_dinv(const int* __restrict__ cnt, float* __restrict__ dinv, int n) {
    int i = blockIdx.x * blockDim.x + threadIdx.x;
    if (i < n) dinv[i] = rsqrtf((float)(cnt[i] + 1));
}

__global__ __launch_bounds__(1024)
void scan_blk(const int* __restrict__ cnt, int* __restrict__ offsets,
              int* __restrict__ blocksum, int n) {
    __shared__ int wsum[16];
    int tid = threadIdx.x;
    int i = blockIdx.x * 1024 + tid;
    int lane = tid & 63, wid = tid >> 6;
    int v = (i < n) ? cnt[i] : 0;
    int x = v;
    #pragma unroll
    for (int off = 1; off < 64; off <<= 1) {
        int t = __shfl_up(x, off, 64);
        if (lane >= off) x += t;
    }
    if (lane == 63) wsum[wid] = x;
    __syncthreads();
    if (wid == 0) {
        int w = (lane < 16) ? wsum[lane] : 0;
        #pragma unroll
        for (int off = 1; off < 16; off <<= 1) {
            int t = __shfl_up(w, off, 64);
            if (lane >= off) w += t;
        }
        if (lane < 16) wsum[lane] = w;
    }
    __syncthreads();
    int waveoff = (wid > 0) ? wsum[wid - 1] : 0;
    if (i < n) offsets[i] = x + waveoff - v;
    if (tid == 1023) blocksum[blockIdx.x] = x + waveoff;
}

__global__ void scan_top(const int* __restrict__ blocksum, int* __restrict__ blockpref,
                         int* __restrict__ offsets, int nb, int n) {
    int lane = threadIdx.x;
    int v = (lane < nb) ? blocksum[lane] : 0;
    int x = v;
    #pragma unroll
    for (int off = 1; off < 64; off <<= 1) {
        int t = __shfl_up(x, off, 64);
        if (lane >= off) x += t;
    }
    if (lane < nb) blockpref[lane] = x - v;
    if (lane == 63) offsets[n] = x;
}

__global__ __launch_bounds__(1024)
void scan_add(int* __restrict__ offsets, int* __restrict__ cursor,
              const int* __restrict__ blockpref, int n) {
    int i = blockIdx.x * 1024 + threadIdx.x;
    if (i < n) {
        int o = offsets[i] + blockpref[blockIdx.x];
        offsets[i] = o;
        cursor[i] = o;
    }
}

__global__ void fill_csr(const int* __restrict__ src, const int* __restrict__ dst,
                         int* __restrict__ cursor, int* __restrict__ csr, int e) {
    int i = blockIdx.x * blockDim.x + threadIdx.x;
    if (i < e) {
        int d = dst[i];
        int pos = atomicAdd(&cursor[d], 1);
        csr[pos] = src[i];
    }
}

// deterministic edge order per node (atomics scramble it run-to-run)
__global__ void sort_csr(int* __restrict__ csr, const int* __restrict__ offsets, int n) {
    int node = blockIdx.x * 256 + threadIdx.x;
    if (node >= n) return;
    int beg = offsets[node], end = offsets[node + 1];
    for (int i = beg + 1; i < end; ++i) {
        int key = csr[i];
        int j = i - 1;
        while (j >= beg && csr[j] > key) { csr[j + 1] = csr[j]; --j; }
        csr[j + 1] = key;
    }
}

// ------------------------------------------------------------------ prep
// x (fp32) -> fp16 gather table, pre-scaled by dinv[row]
__global__ void conv_x(const float4* __restrict__ x, ushort4* __restrict__ o,
                       const float* __restrict__ dinv, int n4) {
    int i = blockIdx.x * 256 + threadIdx.x;
    if (i >= n4) return;
    int row = i >> 5;
    float dv = dinv[row];
    float4 v = x[i];
    ushort4 u;
    u.x = f2h(v.x * dv); u.y = f2h(v.y * dv);
    u.z = f2h(v.z * dv); u.w = f2h(v.w * dv);
    o[i] = u;
}

// weights -> bf16 transposed: W1T[n][k], W2T[n][k], Bt3[k][n(mu|lv)][h]
__global__ void prep_w(const float* __restrict__ W1, const float* __restrict__ W2,
                       const float* __restrict__ Wmu, const float* __restrict__ Wlv,
                       ushort* __restrict__ w1t, ushort* __restrict__ w2t,
                       ushort* __restrict__ bt3) {
    int i = blockIdx.x * 256 + threadIdx.x;
    if (i < 16384) {
        int nn = i >> 7, k = i & 127;
        w1t[i] = f2b(W1[k * 128 + nn]);
    } else if (i < 32768) {
        int j = i - 16384; int nn = j >> 7, k = j & 127;
        w2t[j] = f2b(W2[k * 128 + nn]);
    } else if (i < 98304) {
        int j = i - 32768;                 // ((k*128 + n)*128 + h)
        int h = j & 127; int nk = j >> 7; int nn = nk & 127; int k = nk >> 7;
        float v = (nn < 64) ? Wmu[k * 8192 + h * 64 + nn]
                            : Wlv[k * 8192 + h * 64 + (nn - 64)];
        bt3[j] = f2b(v);
    }
}

// ------------------------------------------------------------------ propagate
// reads fp16 table (rows pre-scaled by dinv[src]), writes bf16:
// out[i] = dinv[i] * (sum_nbr tab[s] + tab[i])
// FROZEN STRUCTURE: 2-deep chains (4-deep variants mis-validate; see R5-R7).
__global__ __launch_bounds__(256)
void prop_b(const ushort* __restrict__ hin, ushort* __restrict__ hout,
            const int* __restrict__ csr, const int* __restrict__ offsets,
            const float* __restrict__ dinv, int n) {
    int gw = blockIdx.x * 4 + (threadIdx.x >> 6);
    if (gw >= n) return;
    int lane = threadIdx.x & 63;
    int grp = lane >> 4, gl = lane & 15;
    int coff = gl << 3;               // element offset within row
    int beg = offsets[gw], end = offsets[gw + 1];
    float a0[8] = {0.f,0.f,0.f,0.f,0.f,0.f,0.f,0.f};
    float a1[8] = {0.f,0.f,0.f,0.f,0.f,0.f,0.f,0.f};
    for (int base = beg; base < end; base += 64) {
        int cnt = end - base; if (cnt > 64) cnt = 64;
        int sidx = (lane < cnt) ? csr[base + lane] : 0;
        int j = grp;
        for (; j + 4 < cnt; j += 8) {
            int s0 = __shfl(sidx, j, 64);
            int s1 = __shfl(sidx, j + 4, 64);
            s16x8 v0 = *(const s16x8*)(hin + (s0 << 7) + coff);
            s16x8 v1 = *(const s16x8*)(hin + (s1 << 7) + coff);
            #pragma unroll
            for (int q = 0; q < 8; ++q) {
                a0[q] += h2f((ushort)v0[q]);
                a1[q] += h2f((ushort)v1[q]);
            }
        }
        if (j < cnt) {
            int s0 = __shfl(sidx, j, 64);
            s16x8 v0 = *(const s16x8*)(hin + (s0 << 7) + coff);
            #pragma unroll
            for (int q = 0; q < 8; ++q) a0[q] += h2f((ushort)v0[q]);
        }
    }
    #pragma unroll
    for (int q = 0; q < 8; ++q) {
        float t = a0[q] + a1[q];
        t += __shfl_xor(t, 16, 64);
        t += __shfl_xor(t, 32, 64);
        a0[q] = t;
    }
    if (grp == 0) {
        s16x8 sv = *(const s16x8*)(hin + (gw << 7) + coff);
        float dn = dinv[gw];
        s16x8 ob;
        #pragma unroll
        for (int q = 0; q < 8; ++q)
            ob[q] = (short)f2b((a0[q] + h2f((ushort)sv[q])) * dn);
        *(s16x8*)(hout + (gw << 7) + coff) = ob;
    }
}

// ------------------------------------------------------------------ MFMA GEMM (M x 128 @ 128 x 128)
// A is bf16 (R3-proven precision for this path); single MFMA, 64 KB LDS.
// C = prelu(A@B + bias, alpha); Ch (fp16 table) = C * dinv[row]
// MODE 1 additionally writes fp32 C to Cf (hgcn output)
template<int MODE>
__global__ __launch_bounds__(256)
void gemm12(const ushort* __restrict__ A, const ushort* __restrict__ Bt,
            const float* __restrict__ bias, const float* __restrict__ alpha,
            const float* __restrict__ dinv,
            float* __restrict__ Cf, ushort* __restrict__ Ch, int nrows) {
    __shared__ char As[32768];
    __shared__ char Bs[32768];
    int tid = threadIdx.x;
    int row0 = blockIdx.x * 128;
    #pragma unroll
    for (int it = 0; it < 8; ++it) {
        int idx = tid + it * 256;
        int r = idx >> 4, cb = (idx & 15) << 4;
        int sw = cb ^ ((r & 15) << 4);
        uint4 v = make_uint4(0, 0, 0, 0);
        int row = row0 + r;
        if (row < nrows) v = *(const uint4*)((const char*)A + (size_t)row * 256 + cb);
        *(uint4*)(As + r * 256 + sw) = v;
        uint4 bv = *(const uint4*)((const char*)Bt + (size_t)idx * 16);
        *(uint4*)(Bs + r * 256 + sw) = bv;
    }
    __syncthreads();

    int w = tid >> 6, lane = tid & 63;
    int bq = lane >> 4, tr = lane & 15;
    f32x4 acc[2][8];
    #pragma unroll
    for (int mi = 0; mi < 2; ++mi)
        #pragma unroll
        for (int nj = 0; nj < 8; ++nj)
            acc[mi][nj] = (f32x4){0.f, 0.f, 0.f, 0.f};

    #pragma unroll
    for (int s = 0; s < 4; ++s) {
        int xoff = (s * 64 + bq * 16) ^ ((tr & 15) << 4);
        s16x8 af[2], bfr[8];
        #pragma unroll
        for (int mi = 0; mi < 2; ++mi)
            af[mi] = *(const s16x8*)(As + (w * 32 + mi * 16 + tr) * 256 + xoff);
        #pragma unroll
        for (int nj = 0; nj < 8; ++nj)
            bfr[nj] = *(const s16x8*)(Bs + (nj * 16 + tr) * 256 + xoff);
        #pragma unroll
        for (int mi = 0; mi < 2; ++mi)
            #pragma unroll
            for (int nj = 0; nj < 8; ++nj)
                acc[mi][nj] = __builtin_amdgcn_mfma_f32_16x16x32_bf16(af[mi], bfr[nj], acc[mi][nj], 0, 0, 0);
    }

    int g = lane >> 4, c = lane & 15;
    float aval = alpha[0];
    float bb[8];
    #pragma unroll
    for (int nj = 0; nj < 8; ++nj) bb[nj] = bias[nj * 16 + c];
    #pragma unroll
    for (int mi = 0; mi < 2; ++mi) {
        #pragma unroll
        for (int j = 0; j < 4; ++j) {
            int row = row0 + w * 32 + mi * 16 + g * 4 + j;
            if (row >= nrows) continue;
            float dv = dinv[row];
            #pragma unroll
            for (int nj = 0; nj < 8; ++nj) {
                int col = nj * 16 + c;
                float t = acc[mi][nj][j] + bb[nj];
                t = t >= 0.f ? t : aval * t;
                if (MODE) Cf[(size_t)row * 128 + col] = t;
                Ch[(size_t)row * 128 + col] = f2h(t * dv);
            }
        }
    }
}

// ------------------------------------------------------------------ mu/lv GEMM (+ fused hk, r)
// A (p) is bf16; single MFMA, 64 KB LDS. blockIdx.x = k; Bt3[k]: cols 0-63 mu, 64-127 lv
template<int FUSED>
__global__ __launch_bounds__(256)
void gemm3(const ushort* __restrict__ A, const ushort* __restrict__ Bt3,
           const float* __restrict__ bmu, const float* __restrict__ blv,
           const float* __restrict__ amu, const float* __restrict__ alv,
           const float* __restrict__ Wr, const float* __restrict__ br,
           const float* __restrict__ eps,
           float* __restrict__ out_mu, float* __restrict__ out_lv,
           float* __restrict__ out_hk, float* __restrict__ out_r, int nrows) {
    __shared__ char As[32768];
    __shared__ char Bs[32768];
    int tid = threadIdx.x;
    int k = blockIdx.x;
    int row0 = blockIdx.y * 128;
    const ushort* Bt = Bt3 + (size_t)k * 16384;
    #pragma unroll
    for (int it = 0; it < 8; ++it) {
        int idx = tid + it * 256;
        int r = idx >> 4, cb = (idx & 15) << 4;
        int sw = cb ^ ((r & 15) << 4);
        uint4 v = make_uint4(0, 0, 0, 0);
        int row = row0 + r;
        if (row < nrows) v = *(const uint4*)((const char*)A + (size_t)row * 256 + cb);
        *(uint4*)(As + r * 256 + sw) = v;
        uint4 bv = *(const uint4*)((const char*)Bt + (size_t)idx * 16);
        *(uint4*)(Bs + r * 256 + sw) = bv;
    }
    __syncthreads();

    int w = tid >> 6, lane = tid & 63;
    int bq = lane >> 4, tr = lane & 15;
    f32x4 acc[2][8];
    #pragma unroll
    for (int mi = 0; mi < 2; ++mi)
        #pragma unroll
        for (int nj = 0; nj < 8; ++nj)
            acc[mi][nj] = (f32x4){0.f, 0.f, 0.f, 0.f};

    #pragma unroll
    for (int s = 0; s < 4; ++s) {
        int xoff = (s * 64 + bq * 16) ^ ((tr & 15) << 4);
        s16x8 af[2], bfr[8];
        #pragma unroll
        for (int mi = 0; mi < 2; ++mi)
            af[mi] = *(const s16x8*)(As + (w * 32 + mi * 16 + tr) * 256 + xoff);
        #pragma unroll
        for (int nj = 0; nj < 8; ++nj)
            bfr[nj] = *(const s16x8*)(Bs + (nj * 16 + tr) * 256 + xoff);
        #pragma unroll
        for (int mi = 0; mi < 2; ++mi)
            #pragma unroll
            for (int nj = 0; nj < 8; ++nj)
                acc[mi][nj] = __builtin_amdgcn_mfma_f32_16x16x32_bf16(af[mi], bfr[nj], acc[mi][nj], 0, 0, 0);
    }

    int g = lane >> 4, c = lane & 15;
    float amuv = amu[k], alvv = alv[k];
    float brk = br[k];
    float bmv[4], blvb[4], wrv[4];
    #pragma unroll
    for (int nj = 0; nj < 4; ++nj) {
        int d = nj * 16 + c;
        bmv[nj] = bmu[k * 64 + d];
        blvb[nj] = blv[k * 64 + d];
        wrv[nj] = FUSED ? Wr[k * 64 + d] : 0.f;
    }
    #pragma unroll
    for (int mi = 0; mi < 2; ++mi) {
        float rsum[4] = {0.f, 0.f, 0.f, 0.f};
        #pragma unroll
        for (int j = 0; j < 4; ++j) {
            int row = row0 + w * 32 + mi * 16 + g * 4 + j;
            if (row >= nrows) continue;
            #pragma unroll
            for (int nj = 0; nj < 4; ++nj) {
                int d = nj * 16 + c;
                size_t oc = (size_t)row * KD + k * 64 + d;
                float m_ = acc[mi][nj][j] + bmv[nj];
                m_ = m_ >= 0.f ? m_ : amuv * m_;
                float l_ = acc[mi][nj + 4][j] + blvb[nj];
                l_ = l_ >= 0.f ? l_ : alvv * l_;
                l_ = 1.f / (1.f + __expf(-l_));
                out_mu[oc] = m_;
                out_lv[oc] = l_;
                if (FUSED) {
                    float h = fmaf(eps[oc], __expf(0.5f * l_), m_);
                    out_hk[oc] = h;
                    rsum[j] = fmaf(h, wrv[nj], rsum[j]);
                }
            }
        }
        if (FUSED) {
            #pragma unroll
            for (int j = 0; j < 4; ++j) {
                float t = rsum[j];
                t += __shfl_xor(t, 1, 64);
                t += __shfl_xor(t, 2, 64);
                t += __shfl_xor(t, 4, 64);
                t += __shfl_xor(t, 8, 64);
                if (c == 0) {
                    int row = row0 + w * 32 + mi * 16 + g * 4 + j;
                    if (row < nrows)
                        out_r[(size_t)row * 4 + k] = 1.f / (1.f + __expf(-(t + brk)));
                }
            }
        }
    }
}

// ------------------------------------------------------------------ fallback reparam + r
__global__ void hk_kernel(const float* __restrict__ mu, const float* __restrict__ lv,
                          const float* __restrict__ eps, const float* __restrict__ Wr,
                          const float* __restrict__ br, float* __restrict__ hk,
                          float* __restrict__ r, int n) {
    int gw = (blockIdx.x * blockDim.x + threadIdx.x) >> 6;
    int lane = threadIdx.x & 63;
    if (gw >= n) return;
    size_t base = (size_t)gw * KD;
    #pragma unroll
    for (int k = 0; k < 4; ++k) {
        int c = k * 64 + lane;
        float m = mu[base + c], v = lv[base + c], e = eps[base + c];
        float h = fmaf(e, __expf(0.5f * v), m);
        hk[base + c] = h;
        float t = h * Wr[k * 64 + lane];
        #pragma unroll
        for (int off = 32; off >= 1; off >>= 1) t += __shfl_xor(t, off, 64);
        if (lane == 0) r[(size_t)gw * 4 + k] = 1.f / (1.f + __expf(-(t + br[k])));
    }
}

// ------------------------------------------------------------------ launch
extern "C" void kernel_launch(void* const* d_in, const int* in_sizes, int n_in,
                              void* d_out, int out_size, void* d_ws, size_t ws_size,
                              hipStream_t stream) {
    const float* x   = (const float*)d_in[0];
    const int*   ei  = (const int*)d_in[1];
    const float* W1  = (const float*)d_in[2];
    const float* b1  = (const float*)d_in[3];
    const float* a1  = (const float*)d_in[4];
    const float* W2  = (const float*)d_in[5];
    const float* b2  = (const float*)d_in[6];
    const float* a2  = (const float*)d_in[7];
    const float* Wmu = (const float*)d_in[8];
    const float* bmu = (const float*)d_in[9];
    const float* amu = (const float*)d_in[10];
    const float* Wlv = (const float*)d_in[11];
    const float* blv = (const float*)d_in[12];
    const float* alv = (const float*)d_in[13];
    const float* Wr  = (const float*)d_in[14];
    const float* br  = (const float*)d_in[15];
    const float* eps = (const float*)d_in[16];

    float* out      = (float*)d_out;
    float* out_hgcn = out;                                  // N*128
    float* out_lv   = out + (size_t)N_NODES * HDIM;         // N*256
    float* out_mu   = out_lv + (size_t)N_NODES * KD;        // N*256
    float* out_hk   = out_mu + (size_t)N_NODES * KD;        // N*256
    float* out_r    = out_hk + (size_t)N_NODES * KD;        // N*4

    char* ws = (char*)d_ws;
    int*    cnt      = (int*)ws;                       // N ints
    int*    offsets  = (int*)(ws + 204800);            // N+1 ints
    int*    cursor   = (int*)(ws + 409600);            // N ints
    int*    csr      = (int*)(ws + 614400);            // E ints
    float*  dinv     = (float*)(ws + 3814400);         // N floats
    ushort* w1t      = (ushort*)(ws + 4014592);        // 16384 bf16
    ushort* w2t      = (ushort*)(ws + 4047360);        // 16384 bf16
    ushort* bt3      = (ushort*)(ws + 4080128);        // 65536 bf16 (ends 4211200)
    int*    blocksum = (int*)(ws + 4211200);           // 49 ints
    int*    blockpref= (int*)(ws + 4211456);           // 49 ints

    // fp16 gather tables in the hk output region (fully rewritten at the end)
    ushort* X16 = (ushort*)out_hk;                      // bytes [0, 12.8M)
    ushort* H16 = X16 + (size_t)N_NODES * HDIM;         // [12.8M, 25.6M)
    ushort* G16 = H16 + (size_t)N_NODES * HDIM;         // [25.6M, 38.4M)

    // bf16 prop outputs (GEMM A operands): q1 in out_mu region, q2 in out_lv
    // region (both dead until gemm3 overwrites them)
    ushort* q1b = (ushort*)out_mu;
    ushort* q2b = (ushort*)out_lv;

    // P (bf16, 12.8MB): ws if it fits, else hk bytes [0,12.8M) (X16 dead by then)
    const size_t P_OFF = 4211712;
    const bool fused = ws_size >= P_OFF + (size_t)N_NODES * HDIM * 2;
    ushort* P = fused ? (ushort*)(ws + P_OFF) : X16;

    const int* e_src = ei;
    const int* e_dst = ei + N_EDGES;
    const int NB = (N_NODES + 1023) / 1024;   // 49

    zero_int <<<(N_NODES + 255) / 256, 256, 0, stream>>>(cnt, N_NODES);
    count_deg<<<(N_EDGES + 255) / 256, 256, 0, stream>>>(e_dst, cnt, N_EDGES);
    calc_dinv<<<(N_NODES + 255) / 256, 256, 0, stream>>>(cnt, dinv, N_NODES);
    scan_blk <<<NB, 1024, 0, stream>>>(cnt, offsets, blocksum, N_NODES);
    scan_top <<<1, 64, 0, stream>>>(blocksum, blockpref, offsets, NB, N_NODES);
    scan_add <<<NB, 1024, 0, stream>>>(offsets, cursor, blockpref, N_NODES);
    fill_csr <<<(N_EDGES + 255) / 256, 256, 0, stream>>>(e_src, e_dst, cursor, csr, N_EDGES);
    sort_csr <<<(N_NODES + 255) / 256, 256, 0, stream>>>(csr, offsets, N_NODES);

    prep_w<<<384, 256, 0, stream>>>(W1, W2, Wmu, Wlv, w1t, w2t, bt3);
    conv_x<<<(N_NODES * 32 + 255) / 256, 256, 0, stream>>>((const float4*)x, (ushort4*)X16, dinv, N_NODES * 32);

    // q1 = prop(x*dinv)            X16 -> q1b (bf16)
    prop_b<<<12500, 256, 0, stream>>>(X16, q1b, csr, offsets, dinv, N_NODES);
    // h = prelu(q1@W1+b1); H16 = fp16(h*dinv)
    gemm12<0><<<391, 256, 0, stream>>>(q1b, w1t, b1, a1, dinv, nullptr, H16, N_NODES);
    // q2 = prop(h*dinv)            H16 -> q2b (bf16)
    prop_b<<<12500, 256, 0, stream>>>(H16, q2b, csr, offsets, dinv, N_NODES);
    // hgcn = prelu(q2@W2+b2) fp32 -> out; G16 = fp16(hgcn*dinv)
    gemm12<1><<<391, 256, 0, stream>>>(q2b, w2t, b2, a2, dinv, out_hgcn, G16, N_NODES);
    // P = prop(hgcn*dinv)          G16 -> P (bf16)
    prop_b<<<12500, 256, 0, stream>>>(G16, P, csr, offsets, dinv, N_NODES);

    dim3 g3(4, 391);
    if (fused) {
        gemm3<1><<<g3, 256, 0, stream>>>(P, bt3, bmu, blv, amu, alv, Wr, br, eps,
                                         out_mu, out_lv, out_hk, out_r, N_NODES);
    } else {
        gemm3<0><<<g3, 256, 0, stream>>>(P, bt3, bmu, blv, amu, alv, Wr, br, eps,
                                         out_mu, out_lv, out_hk, out_r, N_NODES);
        hk_kernel<<<12500, 256, 0, stream>>>(out_mu, out_lv, eps, Wr, br, out_hk, out_r, N_NODES);
    }
}

// Round 11
// 310.571 us; speedup vs baseline: 1.4034x; 1.2191x over previous
//
#include <hip/hip_runtime.h>
#include <math.h>

#define N_NODES 50000
#define N_EDGES 800000
#define HDIM 128
#define KD 256   // K*D

typedef float f32x4 __attribute__((ext_vector_type(4)));
typedef short s16x8 __attribute__((ext_vector_type(8)));

__device__ __forceinline__ ushort f2b(float f) {        // fp32 -> bf16 RNE
    union { float f; unsigned u; } x; x.f = f;
    unsigned u = x.u;
    return (ushort)((u + 0x7FFF + ((u >> 16) & 1)) >> 16);
}
__device__ __forceinline__ float b2f(ushort h) {
    union { unsigned u; float f; } x; x.u = ((unsigned)h) << 16; return x.f;
}
__device__ __forceinline__ ushort f2h(float f) {        // fp32 -> fp16 RNE
    union { _Float16 h; ushort u; } x; x.h = (_Float16)f; return x.u;
}
__device__ __forceinline__ float h2f(ushort u) {
    union { ushort u; _Float16 h; } x; x.u = u; return (float)x.h;
}

// ------------------------------------------------------------------ CSR build
__global__ void zero_int(int* __restrict__ p, int n) {
    int i = blockIdx.x * blockDim.x + threadIdx.x;
    if (i < n) p[i] = 0;
}

__global__ void count_deg(const int* __restrict__ dst, int* __restrict__ cnt, int e) {
    int i = blockIdx.x * blockDim.x + threadIdx.x;
    if (i < e) atomicAdd(&cnt[dst[i]], 1);
}

// block-local exclusive scans + per-block totals; also emits dinv (free here)
__global__ __launch_bounds__(1024)
void scan_blk(const int* __restrict__ cnt, int* __restrict__ offsets,
              int* __restrict__ blocksum, float* __restrict__ dinv, int n) {
    __shared__ int wsum[16];
    int tid = threadIdx.x;
    int i = blockIdx.x * 1024 + tid;
    int lane = tid & 63, wid = tid >> 6;
    int v = (i < n) ? cnt[i] : 0;
    if (i < n) dinv[i] = rsqrtf((float)(v + 1));   // +1 self loop
    int x = v;
    #pragma unroll
    for (int off = 1; off < 64; off <<= 1) {
        int t = __shfl_up(x, off, 64);
        if (lane >= off) x += t;
    }
    if (lane == 63) wsum[wid] = x;
    __syncthreads();
    if (wid == 0) {
        int w = (lane < 16) ? wsum[lane] : 0;
        #pragma unroll
        for (int off = 1; off < 16; off <<= 1) {
            int t = __shfl_up(w, off, 64);
            if (lane >= off) w += t;
        }
        if (lane < 16) wsum[lane] = w;
    }
    __syncthreads();
    int waveoff = (wid > 0) ? wsum[wid - 1] : 0;
    if (i < n) offsets[i] = x + waveoff - v;
    if (tid == 1023) blocksum[blockIdx.x] = x + waveoff;
}

__global__ void scan_top(const int* __restrict__ blocksum, int* __restrict__ blockpref,
                         int* __restrict__ offsets, int nb, int n) {
    int lane = threadIdx.x;
    int v = (lane < nb) ? blocksum[lane] : 0;
    int x = v;
    #pragma unroll
    for (int off = 1; off < 64; off <<= 1) {
        int t = __shfl_up(x, off, 64);
        if (lane >= off) x += t;
    }
    if (lane < nb) blockpref[lane] = x - v;
    if (lane == 63) offsets[n] = x;
}

__global__ __launch_bounds__(1024)
void scan_add(int* __restrict__ offsets, int* __restrict__ cursor,
              const int* __restrict__ blockpref, int n) {
    int i = blockIdx.x * 1024 + threadIdx.x;
    if (i < n) {
        int o = offsets[i] + blockpref[blockIdx.x];
        offsets[i] = o;
        cursor[i] = o;
    }
}

__global__ void fill_csr(const int* __restrict__ src, const int* __restrict__ dst,
                         int* __restrict__ cursor, int* __restrict__ csr, int e) {
    int i = blockIdx.x * blockDim.x + threadIdx.x;
    if (i < e) {
        int d = dst[i];
        int pos = atomicAdd(&cursor[d], 1);
        csr[pos] = src[i];
    }
}

// deterministic edge order per node (atomics scramble it run-to-run).
// Wave-per-node bitonic sort via shfl (deg<=64); serial fallback for deg>64.
// Result: ascending — identical array to insertion sort (dupes are equal ints).
__global__ __launch_bounds__(256)
void sort_csr(int* __restrict__ csr, const int* __restrict__ offsets, int n) {
    int node = blockIdx.x * 4 + (threadIdx.x >> 6);
    if (node >= n) return;
    int lane = threadIdx.x & 63;
    int beg = offsets[node], end = offsets[node + 1];
    int deg = end - beg;
    if (deg <= 1) return;
    if (deg <= 64) {
        int v = (lane < deg) ? csr[beg + lane] : 0x7FFFFFFF;
        #pragma unroll
        for (int k = 2; k <= 64; k <<= 1) {
            #pragma unroll
            for (int j = k >> 1; j >= 1; j >>= 1) {
                int p = __shfl_xor(v, j, 64);
                bool up = ((lane & k) == 0);          // ascending block
                bool keepMin = (((lane & j) == 0) == up);
                v = keepMin ? (v < p ? v : p) : (v > p ? v : p);
            }
        }
        if (lane < deg) csr[beg + lane] = v;
    } else if (lane == 0) {
        for (int i = beg + 1; i < end; ++i) {
            int key = csr[i];
            int j = i - 1;
            while (j >= beg && csr[j] > key) { csr[j + 1] = csr[j]; --j; }
            csr[j + 1] = key;
        }
    }
}

// ------------------------------------------------------------------ prep
// x (fp32) -> fp16 gather table, pre-scaled by dinv[row]
__global__ void conv_x(const float4* __restrict__ x, ushort4* __restrict__ o,
                       const float* __restrict__ dinv, int n4) {
    int i = blockIdx.x * 256 + threadIdx.x;
    if (i >= n4) return;
    int row = i >> 5;
    float dv = dinv[row];
    float4 v = x[i];
    ushort4 u;
    u.x = f2h(v.x * dv); u.y = f2h(v.y * dv);
    u.z = f2h(v.z * dv); u.w = f2h(v.w * dv);
    o[i] = u;
}

// weights -> bf16 transposed: W1T[n][k], W2T[n][k], Bt3[k][n(mu|lv)][h]
__global__ void prep_w(const float* __restrict__ W1, const float* __restrict__ W2,
                       const float* __restrict__ Wmu, const float* __restrict__ Wlv,
                       ushort* __restrict__ w1t, ushort* __restrict__ w2t,
                       ushort* __restrict__ bt3) {
    int i = blockIdx.x * 256 + threadIdx.x;
    if (i < 16384) {
        int nn = i >> 7, k = i & 127;
        w1t[i] = f2b(W1[k * 128 + nn]);
    } else if (i < 32768) {
        int j = i - 16384; int nn = j >> 7, k = j & 127;
        w2t[j] = f2b(W2[k * 128 + nn]);
    } else if (i < 98304) {
        int j = i - 32768;                 // ((k*128 + n)*128 + h)
        int h = j & 127; int nk = j >> 7; int nn = nk & 127; int k = nk >> 7;
        float v = (nn < 64) ? Wmu[k * 8192 + h * 64 + nn]
                            : Wlv[k * 8192 + h * 64 + (nn - 64)];
        bt3[j] = f2b(v);
    }
}

// ------------------------------------------------------------------ propagate
// reads fp16 table (rows pre-scaled by dinv[src]), writes bf16:
// out[i] = dinv[i] * (sum_nbr tab[s] + tab[i])
// FROZEN STRUCTURE: 2-deep chains (4-deep variants mis-validate; see R5-R7).
__global__ __launch_bounds__(256)
void prop_b(const ushort* __restrict__ hin, ushort* __restrict__ hout,
            const int* __restrict__ csr, const int* __restrict__ offsets,
            const float* __restrict__ dinv, int n) {
    int gw = blockIdx.x * 4 + (threadIdx.x >> 6);
    if (gw >= n) return;
    int lane = threadIdx.x & 63;
    int grp = lane >> 4, gl = lane & 15;
    int coff = gl << 3;               // element offset within row
    int beg = offsets[gw], end = offsets[gw + 1];
    float a0[8] = {0.f,0.f,0.f,0.f,0.f,0.f,0.f,0.f};
    float a1[8] = {0.f,0.f,0.f,0.f,0.f,0.f,0.f,0.f};
    for (int base = beg; base < end; base += 64) {
        int cnt = end - base; if (cnt > 64) cnt = 64;
        int sidx = (lane < cnt) ? csr[base + lane] : 0;
        int j = grp;
        for (; j + 4 < cnt; j += 8) {
            int s0 = __shfl(sidx, j, 64);
            int s1 = __shfl(sidx, j + 4, 64);
            s16x8 v0 = *(const s16x8*)(hin + (s0 << 7) + coff);
            s16x8 v1 = *(const s16x8*)(hin + (s1 << 7) + coff);
            #pragma unroll
            for (int q = 0; q < 8; ++q) {
                a0[q] += h2f((ushort)v0[q]);
                a1[q] += h2f((ushort)v1[q]);
            }
        }
        if (j < cnt) {
            int s0 = __shfl(sidx, j, 64);
            s16x8 v0 = *(const s16x8*)(hin + (s0 << 7) + coff);
            #pragma unroll
            for (int q = 0; q < 8; ++q) a0[q] += h2f((ushort)v0[q]);
        }
    }
    #pragma unroll
    for (int q = 0; q < 8; ++q) {
        float t = a0[q] + a1[q];
        t += __shfl_xor(t, 16, 64);
        t += __shfl_xor(t, 32, 64);
        a0[q] = t;
    }
    if (grp == 0) {
        s16x8 sv = *(const s16x8*)(hin + (gw << 7) + coff);
        float dn = dinv[gw];
        s16x8 ob;
        #pragma unroll
        for (int q = 0; q < 8; ++q)
            ob[q] = (short)f2b((a0[q] + h2f((ushort)sv[q])) * dn);
        *(s16x8*)(hout + (gw << 7) + coff) = ob;
    }
}

// ------------------------------------------------------------------ MFMA GEMM (M x 128 @ 128 x 128)
// A is bf16; single MFMA, 64 KB LDS.
// C = prelu(A@B + bias, alpha); Ch (fp16 table) = C * dinv[row]
// MODE 1 additionally writes fp32 C to Cf (hgcn output)
template<int MODE>
__global__ __launch_bounds__(256)
void gemm12(const ushort* __restrict__ A, const ushort* __restrict__ Bt,
            const float* __restrict__ bias, const float* __restrict__ alpha,
            const float* __restrict__ dinv,
            float* __restrict__ Cf, ushort* __restrict__ Ch, int nrows) {
    __shared__ char As[32768];
    __shared__ char Bs[32768];
    int tid = threadIdx.x;
    int row0 = blockIdx.x * 128;
    #pragma unroll
    for (int it = 0; it < 8; ++it) {
        int idx = tid + it * 256;
        int r = idx >> 4, cb = (idx & 15) << 4;
        int sw = cb ^ ((r & 15) << 4);
        uint4 v = make_uint4(0, 0, 0, 0);
        int row = row0 + r;
        if (row < nrows) v = *(const uint4*)((const char*)A + (size_t)row * 256 + cb);
        *(uint4*)(As + r * 256 + sw) = v;
        uint4 bv = *(const uint4*)((const char*)Bt + (size_t)idx * 16);
        *(uint4*)(Bs + r * 256 + sw) = bv;
    }
    __syncthreads();

    int w = tid >> 6, lane = tid & 63;
    int bq = lane >> 4, tr = lane & 15;
    f32x4 acc[2][8];
    #pragma unroll
    for (int mi = 0; mi < 2; ++mi)
        #pragma unroll
        for (int nj = 0; nj < 8; ++nj)
            acc[mi][nj] = (f32x4){0.f, 0.f, 0.f, 0.f};

    #pragma unroll
    for (int s = 0; s < 4; ++s) {
        int xoff = (s * 64 + bq * 16) ^ ((tr & 15) << 4);
        s16x8 af[2], bfr[8];
        #pragma unroll
        for (int mi = 0; mi < 2; ++mi)
            af[mi] = *(const s16x8*)(As + (w * 32 + mi * 16 + tr) * 256 + xoff);
        #pragma unroll
        for (int nj = 0; nj < 8; ++nj)
            bfr[nj] = *(const s16x8*)(Bs + (nj * 16 + tr) * 256 + xoff);
        #pragma unroll
        for (int mi = 0; mi < 2; ++mi)
            #pragma unroll
            for (int nj = 0; nj < 8; ++nj)
                acc[mi][nj] = __builtin_amdgcn_mfma_f32_16x16x32_bf16(af[mi], bfr[nj], acc[mi][nj], 0, 0, 0);
    }

    int g = lane >> 4, c = lane & 15;
    float aval = alpha[0];
    float bb[8];
    #pragma unroll
    for (int nj = 0; nj < 8; ++nj) bb[nj] = bias[nj * 16 + c];
    #pragma unroll
    for (int mi = 0; mi < 2; ++mi) {
        #pragma unroll
        for (int j = 0; j < 4; ++j) {
            int row = row0 + w * 32 + mi * 16 + g * 4 + j;
            if (row >= nrows) continue;
            float dv = dinv[row];
            #pragma unroll
            for (int nj = 0; nj < 8; ++nj) {
                int col = nj * 16 + c;
                float t = acc[mi][nj][j] + bb[nj];
                t = t >= 0.f ? t : aval * t;
                if (MODE) Cf[(size_t)row * 128 + col] = t;
                Ch[(size_t)row * 128 + col] = f2h(t * dv);
            }
        }
    }
}

// ------------------------------------------------------------------ mu/lv GEMM (+ fused hk, r)
// A (p) is bf16; single MFMA, 64 KB LDS. blockIdx.x = k; Bt3[k]: cols 0-63 mu, 64-127 lv
template<int FUSED>
__global__ __launch_bounds__(256)
void gemm3(const ushort* __restrict__ A, const ushort* __restrict__ Bt3,
           const float* __restrict__ bmu, const float* __restrict__ blv,
           const float* __restrict__ amu, const float* __restrict__ alv,
           const float* __restrict__ Wr, const float* __restrict__ br,
           const float* __restrict__ eps,
           float* __restrict__ out_mu, float* __restrict__ out_lv,
           float* __restrict__ out_hk, float* __restrict__ out_r, int nrows) {
    __shared__ char As[32768];
    __shared__ char Bs[32768];
    int tid = threadIdx.x;
    int k = blockIdx.x;
    int row0 = blockIdx.y * 128;
    const ushort* Bt = Bt3 + (size_t)k * 16384;
    #pragma unroll
    for (int it = 0; it < 8; ++it) {
        int idx = tid + it * 256;
        int r = idx >> 4, cb = (idx & 15) << 4;
        int sw = cb ^ ((r & 15) << 4);
        uint4 v = make_uint4(0, 0, 0, 0);
        int row = row0 + r;
        if (row < nrows) v = *(const uint4*)((const char*)A + (size_t)row * 256 + cb);
        *(uint4*)(As + r * 256 + sw) = v;
        uint4 bv = *(const uint4*)((const char*)Bt + (size_t)idx * 16);
        *(uint4*)(Bs + r * 256 + sw) = bv;
    }
    __syncthreads();

    int w = tid >> 6, lane = tid & 63;
    int bq = lane >> 4, tr = lane & 15;
    f32x4 acc[2][8];
    #pragma unroll
    for (int mi = 0; mi < 2; ++mi)
        #pragma unroll
        for (int nj = 0; nj < 8; ++nj)
            acc[mi][nj] = (f32x4){0.f, 0.f, 0.f, 0.f};

    #pragma unroll
    for (int s = 0; s < 4; ++s) {
        int xoff = (s * 64 + bq * 16) ^ ((tr & 15) << 4);
        s16x8 af[2], bfr[8];
        #pragma unroll
        for (int mi = 0; mi < 2; ++mi)
            af[mi] = *(const s16x8*)(As + (w * 32 + mi * 16 + tr) * 256 + xoff);
        #pragma unroll
        for (int nj = 0; nj < 8; ++nj)
            bfr[nj] = *(const s16x8*)(Bs + (nj * 16 + tr) * 256 + xoff);
        #pragma unroll
        for (int mi = 0; mi < 2; ++mi)
            #pragma unroll
            for (int nj = 0; nj < 8; ++nj)
                acc[mi][nj] = __builtin_amdgcn_mfma_f32_16x16x32_bf16(af[mi], bfr[nj], acc[mi][nj], 0, 0, 0);
    }

    int g = lane >> 4, c = lane & 15;
    float amuv = amu[k], alvv = alv[k];
    float brk = br[k];
    float bmv[4], blvb[4], wrv[4];
    #pragma unroll
    for (int nj = 0; nj < 4; ++nj) {
        int d = nj * 16 + c;
        bmv[nj] = bmu[k * 64 + d];
        blvb[nj] = blv[k * 64 + d];
        wrv[nj] = FUSED ? Wr[k * 64 + d] : 0.f;
    }
    #pragma unroll
    for (int mi = 0; mi < 2; ++mi) {
        float rsum[4] = {0.f, 0.f, 0.f, 0.f};
        #pragma unroll
        for (int j = 0; j < 4; ++j) {
            int row = row0 + w * 32 + mi * 16 + g * 4 + j;
            if (row >= nrows) continue;
            #pragma unroll
            for (int nj = 0; nj < 4; ++nj) {
                int d = nj * 16 + c;
                size_t oc = (size_t)row * KD + k * 64 + d;
                float m_ = acc[mi][nj][j] + bmv[nj];
                m_ = m_ >= 0.f ? m_ : amuv * m_;
                float l_ = acc[mi][nj + 4][j] + blvb[nj];
                l_ = l_ >= 0.f ? l_ : alvv * l_;
                l_ = 1.f / (1.f + __expf(-l_));
                out_mu[oc] = m_;
                out_lv[oc] = l_;
                if (FUSED) {
                    float h = fmaf(eps[oc], __expf(0.5f * l_), m_);
                    out_hk[oc] = h;
                    rsum[j] = fmaf(h, wrv[nj], rsum[j]);
                }
            }
        }
        if (FUSED) {
            #pragma unroll
            for (int j = 0; j < 4; ++j) {
                float t = rsum[j];
                t += __shfl_xor(t, 1, 64);
                t += __shfl_xor(t, 2, 64);
                t += __shfl_xor(t, 4, 64);
                t += __shfl_xor(t, 8, 64);
                if (c == 0) {
                    int row = row0 + w * 32 + mi * 16 + g * 4 + j;
                    if (row < nrows)
                        out_r[(size_t)row * 4 + k] = 1.f / (1.f + __expf(-(t + brk)));
                }
            }
        }
    }
}

// ------------------------------------------------------------------ fallback reparam + r
__global__ void hk_kernel(const float* __restrict__ mu, const float* __restrict__ lv,
                          const float* __restrict__ eps, const float* __restrict__ Wr,
                          const float* __restrict__ br, float* __restrict__ hk,
                          float* __restrict__ r, int n) {
    int gw = (blockIdx.x * blockDim.x + threadIdx.x) >> 6;
    int lane = threadIdx.x & 63;
    if (gw >= n) return;
    size_t base = (size_t)gw * KD;
    #pragma unroll
    for (int k = 0; k < 4; ++k) {
        int c = k * 64 + lane;
        float m = mu[base + c], v = lv[base + c], e = eps[base + c];
        float h = fmaf(e, __expf(0.5f * v), m);
        hk[base + c] = h;
        float t = h * Wr[k * 64 + lane];
        #pragma unroll
        for (int off = 32; off >= 1; off >>= 1) t += __shfl_xor(t, off, 64);
        if (lane == 0) r[(size_t)gw * 4 + k] = 1.f / (1.f + __expf(-(t + br[k])));
    }
}

// ------------------------------------------------------------------ launch
extern "C" void kernel_launch(void* const* d_in, const int* in_sizes, int n_in,
                              void* d_out, int out_size, void* d_ws, size_t ws_size,
                              hipStream_t stream) {
    const float* x   = (const float*)d_in[0];
    const int*   ei  = (const int*)d_in[1];
    const float* W1  = (const float*)d_in[2];
    const float* b1  = (const float*)d_in[3];
    const float* a1  = (const float*)d_in[4];
    const float* W2  = (const float*)d_in[5];
    const float* b2  = (const float*)d_in[6];
    const float* a2  = (const float*)d_in[7];
    const float* Wmu = (const float*)d_in[8];
    const float* bmu = (const float*)d_in[9];
    const float* amu = (const float*)d_in[10];
    const float* Wlv = (const float*)d_in[11];
    const float* blv = (const float*)d_in[12];
    const float* alv = (const float*)d_in[13];
    const float* Wr  = (const float*)d_in[14];
    const float* br  = (const float*)d_in[15];
    const float* eps = (const float*)d_in[16];

    float* out      = (float*)d_out;
    float* out_hgcn = out;                                  // N*128
    float* out_lv   = out + (size_t)N_NODES * HDIM;         // N*256
    float* out_mu   = out_lv + (size_t)N_NODES * KD;        // N*256
    float* out_hk   = out_mu + (size_t)N_NODES * KD;        // N*256
    float* out_r    = out_hk + (size_t)N_NODES * KD;        // N*4

    char* ws = (char*)d_ws;
    int*    cnt      = (int*)ws;                       // N ints
    int*    offsets  = (int*)(ws + 204800);            // N+1 ints
    int*    cursor   = (int*)(ws + 409600);            // N ints
    int*    csr      = (int*)(ws + 614400);            // E ints
    float*  dinv     = (float*)(ws + 3814400);         // N floats
    ushort* w1t      = (ushort*)(ws + 4014592);        // 16384 bf16
    ushort* w2t      = (ushort*)(ws + 4047360);        // 16384 bf16
    ushort* bt3      = (ushort*)(ws + 4080128);        // 65536 bf16 (ends 4211200)
    int*    blocksum = (int*)(ws + 4211200);           // 49 ints
    int*    blockpref= (int*)(ws + 4211456);           // 49 ints

    // fp16 gather tables in the hk output region (fully rewritten at the end)
    ushort* X16 = (ushort*)out_hk;                      // bytes [0, 12.8M)
    ushort* H16 = X16 + (size_t)N_NODES * HDIM;         // [12.8M, 25.6M)
    ushort* G16 = H16 + (size_t)N_NODES * HDIM;         // [25.6M, 38.4M)

    // bf16 prop outputs (GEMM A operands): q1 in out_mu region, q2 in out_lv
    // region (both dead until gemm3 overwrites them)
    ushort* q1b = (ushort*)out_mu;
    ushort* q2b = (ushort*)out_lv;

    // P (bf16, 12.8MB): ws if it fits, else hk bytes [0,12.8M) (X16 dead by then)
    const size_t P_OFF = 4211712;
    const bool fused = ws_size >= P_OFF + (size_t)N_NODES * HDIM * 2;
    ushort* P = fused ? (ushort*)(ws + P_OFF) : X16;

    const int* e_src = ei;
    const int* e_dst = ei + N_EDGES;
    const int NB = (N_NODES + 1023) / 1024;   // 49

    zero_int <<<(N_NODES + 255) / 256, 256, 0, stream>>>(cnt, N_NODES);
    count_deg<<<(N_EDGES + 255) / 256, 256, 0, stream>>>(e_dst, cnt, N_EDGES);
    scan_blk <<<NB, 1024, 0, stream>>>(cnt, offsets, blocksum, dinv, N_NODES);
    scan_top <<<1, 64, 0, stream>>>(blocksum, blockpref, offsets, NB, N_NODES);
    scan_add <<<NB, 1024, 0, stream>>>(offsets, cursor, blockpref, N_NODES);
    fill_csr <<<(N_EDGES + 255) / 256, 256, 0, stream>>>(e_src, e_dst, cursor, csr, N_EDGES);
    sort_csr <<<12500, 256, 0, stream>>>(csr, offsets, N_NODES);

    prep_w<<<384, 256, 0, stream>>>(W1, W2, Wmu, Wlv, w1t, w2t, bt3);
    conv_x<<<(N_NODES * 32 + 255) / 256, 256, 0, stream>>>((const float4*)x, (ushort4*)X16, dinv, N_NODES * 32);

    // q1 = prop(x*dinv)            X16 -> q1b (bf16)
    prop_b<<<12500, 256, 0, stream>>>(X16, q1b, csr, offsets, dinv, N_NODES);
    // h = prelu(q1@W1+b1); H16 = fp16(h*dinv)
    gemm12<0><<<391, 256, 0, stream>>>(q1b, w1t, b1, a1, dinv, nullptr, H16, N_NODES);
    // q2 = prop(h*dinv)            H16 -> q2b (bf16)
    prop_b<<<12500, 256, 0, stream>>>(H16, q2b, csr, offsets, dinv, N_NODES);
    // hgcn = prelu(q2@W2+b2) fp32 -> out; G16 = fp16(hgcn*dinv)
    gemm12<1><<<391, 256, 0, stream>>>(q2b, w2t, b2, a2, dinv, out_hgcn, G16, N_NODES);
    // P = prop(hgcn*dinv)          G16 -> P (bf16)
    prop_b<<<12500, 256, 0, stream>>>(G16, P, csr, offsets, dinv, N_NODES);

    dim3 g3(4, 391);
    if (fused) {
        gemm3<1><<<g3, 256, 0, stream>>>(P, bt3, bmu, blv, amu, alv, Wr, br, eps,
                                         out_mu, out_lv, out_hk, out_r, N_NODES);
    } else {
        gemm3<0><<<g3, 256, 0, stream>>>(P, bt3, bmu, blv, amu, alv, Wr, br, eps,
                                         out_mu, out_lv, out_hk, out_r, N_NODES);
        hk_kernel<<<12500, 256, 0, stream>>>(out_mu, out_lv, eps, Wr, br, out_hk, out_r, N_NODES);
    }
}